// Round 1
// baseline (989.069 us; speedup 1.0000x reference)
//
#include <hip/hip_runtime.h>
#include <hip/hip_bf16.h>
#include <math.h>

typedef __bf16 v8bf __attribute__((ext_vector_type(8)));
typedef __bf16 v4bf __attribute__((ext_vector_type(4)));
typedef float  v4f  __attribute__((ext_vector_type(4)));

__device__ __forceinline__ float wave_reduce_sum(float v) {
#pragma unroll
    for (int m = 1; m < 64; m <<= 1) v += __shfl_xor(v, m, 64);
    return v;
}

__device__ __forceinline__ unsigned fenc(float x) {
    unsigned u = __float_as_uint(x);
    return (u & 0x80000000u) ? ~u : (u | 0x80000000u);
}
__device__ __forceinline__ float fdec(unsigned k) {
    return (k & 0x80000000u) ? __uint_as_float(k ^ 0x80000000u) : __uint_as_float(~k);
}

// ---------------- conversion kernels ----------------

__global__ __launch_bounds__(256) void cvt_f32_bf16(const float* __restrict__ in,
                                                    __bf16* __restrict__ out, long long n) {
    long long i = ((long long)blockIdx.x * 256 + threadIdx.x) * 4;
    if (i >= n) return;
    v4f v = *(const v4f*)(in + i);
    v4bf o;
    o[0] = (__bf16)v[0]; o[1] = (__bf16)v[1]; o[2] = (__bf16)v[2]; o[3] = (__bf16)v[3];
    *(v4bf*)(out + i) = o;
}

// out[c][r] = (bf16) in[r][c];  R,C multiples of 32
__global__ __launch_bounds__(256) void cvt_t_bf16(const float* __restrict__ in,
                                                  __bf16* __restrict__ out, int R, int C) {
    __shared__ float tile[32][33];
    int cb = blockIdx.x * 32, rb = blockIdx.y * 32;
    int tx = threadIdx.x & 31, ty = threadIdx.x >> 5;  // ty in 0..7
#pragma unroll
    for (int i = 0; i < 32; i += 8)
        tile[ty + i][tx] = in[(size_t)(rb + ty + i) * C + cb + tx];
    __syncthreads();
#pragma unroll
    for (int i = 0; i < 32; i += 8)
        out[(size_t)(cb + ty + i) * R + rb + tx] = (__bf16)tile[tx][ty + i];
}

// ---------------- generic bf16 MFMA GEMM: out = A (MxK) @ Bt^T (Bt is NxK) ----------------
// MODE 0: outB (bf16, plain)  = acc (+addMat f32 if non-null)
// MODE 1: outB (bf16, TRANSPOSED write [n][m]) = acc (+addMat read plain [m][n])
// MODE 2: outF (f32, plain)   = acc (+= if accumFlag)
// MODE 3: fused row-dot: atomicAdd(qOut[m], sum_n acc[m][n]*rbDot[m][n])
// MODE 4: outF[m][n] = addMat[m][n] + (maskRow[m] ? acc + addRow[n] : 0)
template <int MODE>
__global__ __launch_bounds__(256) void gemm_bt(
    const __bf16* __restrict__ Ap, const __bf16* __restrict__ Btp,
    int M, int N, int K,
    const float* __restrict__ addMat,
    float* __restrict__ outF,
    __bf16* __restrict__ outB,
    int accumFlag,
    const __bf16* __restrict__ rbDot,
    float* __restrict__ qOut,
    const float* __restrict__ addRow,
    const int* __restrict__ maskRow) {
    __shared__ alignas(16) __bf16 As[64][72];
    __shared__ alignas(16) __bf16 Bs[64][72];
    const int m0 = blockIdx.x * 64, n0 = blockIdx.y * 64;
    const int t = threadIdx.x;
    const int lane = t & 63, wid = t >> 6;
    const int wm = wid >> 1, wn = wid & 1;
    v4f acc[2][2] = {};

    for (int kt = 0; kt < K; kt += 64) {
#pragma unroll
        for (int s2 = 0; s2 < 2; ++s2) {
            int c = t + s2 * 256;
            int row = c >> 3, ch = c & 7;
            *(v8bf*)&As[row][ch * 8] = *(const v8bf*)(Ap + (size_t)(m0 + row) * K + kt + ch * 8);
            *(v8bf*)&Bs[row][ch * 8] = *(const v8bf*)(Btp + (size_t)(n0 + row) * K + kt + ch * 8);
        }
        __syncthreads();
#pragma unroll
        for (int ks = 0; ks < 2; ++ks) {
            const int kl = ks * 32 + ((lane >> 4) << 3);
            v8bf af[2], bfr[2];
#pragma unroll
            for (int f = 0; f < 2; ++f) {
                af[f]  = *(const v8bf*)&As[wm * 32 + f * 16 + (lane & 15)][kl];
                bfr[f] = *(const v8bf*)&Bs[wn * 32 + f * 16 + (lane & 15)][kl];
            }
#pragma unroll
            for (int i = 0; i < 2; ++i)
#pragma unroll
                for (int j = 0; j < 2; ++j)
                    acc[i][j] = __builtin_amdgcn_mfma_f32_16x16x32_bf16(af[i], bfr[j], acc[i][j], 0, 0, 0);
        }
        __syncthreads();
    }

    const int cc = lane & 15, r4 = (lane >> 4) << 2;
    if constexpr (MODE == 3) {
#pragma unroll
        for (int i = 0; i < 2; ++i)
#pragma unroll
            for (int r = 0; r < 4; ++r) {
                const int gm = m0 + wm * 32 + i * 16 + r4 + r;
                float p = 0.f;
#pragma unroll
                for (int j = 0; j < 2; ++j) {
                    const int gn = n0 + wn * 32 + j * 16 + cc;
                    p += acc[i][j][r] * (float)rbDot[(size_t)gm * N + gn];
                }
                p += __shfl_xor(p, 1, 64);
                p += __shfl_xor(p, 2, 64);
                p += __shfl_xor(p, 4, 64);
                p += __shfl_xor(p, 8, 64);
                if (cc == 0) atomicAdd(qOut + gm, p);
            }
    } else {
#pragma unroll
        for (int i = 0; i < 2; ++i)
#pragma unroll
            for (int j = 0; j < 2; ++j)
#pragma unroll
                for (int r = 0; r < 4; ++r) {
                    const int gm = m0 + wm * 32 + i * 16 + r4 + r;
                    const int gn = n0 + wn * 32 + j * 16 + cc;
                    float v = acc[i][j][r];
                    if constexpr (MODE == 0) {
                        if (addMat) v += addMat[(size_t)gm * N + gn];
                        outB[(size_t)gm * N + gn] = (__bf16)v;
                    } else if constexpr (MODE == 1) {
                        if (addMat) v += addMat[(size_t)gm * N + gn];
                        outB[(size_t)gn * M + gm] = (__bf16)v;
                    } else if constexpr (MODE == 2) {
                        if (accumFlag) v += outF[(size_t)gm * N + gn];
                        outF[(size_t)gm * N + gn] = v;
                    } else {  // MODE 4
                        float u = addMat[(size_t)gm * N + gn];
                        if (maskRow[gm]) u += v + addRow[gn];
                        outF[(size_t)gm * N + gn] = u;
                    }
                }
    }
}

// ---------------- small custom kernels ----------------

__global__ __launch_bounds__(256) void beta_kernel(
    const float* __restrict__ b_rel, const float* __restrict__ b_sbj, const float* __restrict__ b_obj,
    const float* __restrict__ Wsr, const float* __restrict__ Wor,
    float* __restrict__ bs, float* __restrict__ bo, int D) {
    int j = blockIdx.x * 256 + threadIdx.x;
    if (j < D) {
        float a = b_sbj[j];
        for (int d = 0; d < D; ++d) a += b_rel[d] * Wsr[(size_t)d * D + j];
        bs[j] = a;
    } else if (j < 2 * D) {
        int jj = j - D;
        float a = b_obj[jj];
        for (int d = 0; d < D; ++d) a += b_rel[d] * Wor[(size_t)d * D + jj];
        bo[jj] = a;
    }
}

__global__ __launch_bounds__(256) void pbeta_kernel(const float* __restrict__ bs,
                                                    const float* __restrict__ bo,
                                                    const __bf16* __restrict__ Ks,
                                                    const __bf16* __restrict__ Ko,
                                                    float* __restrict__ pb, int D) {
    int d = blockIdx.x * 4 + (threadIdx.x >> 6);
    int lane = threadIdx.x & 63;
    float a = 0.f;
    for (int j = lane; j < D; j += 64)
        a += bs[j] * (float)Ko[(size_t)d * D + j] + bo[j] * (float)Ks[(size_t)d * D + j];
    a = wave_reduce_sum(a);
    if (lane == 0) pb[d] = a;
}

__global__ __launch_bounds__(256) void node_kernel(
    const __bf16* __restrict__ Ab, const __bf16* __restrict__ Cb,
    const __bf16* __restrict__ Bb, const __bf16* __restrict__ Db,
    const float* __restrict__ bs, const float* __restrict__ bo,
    float* __restrict__ nodeS, float* __restrict__ nodeO, int Nn, int D) {
    int n = blockIdx.x * 4 + (threadIdx.x >> 6);
    int lane = threadIdx.x & 63;
    int d0 = lane * 16;
    const __bf16* pa = Ab + (size_t)n * D + d0;
    const __bf16* pc = Cb + (size_t)n * D + d0;
    const __bf16* pB = Bb + (size_t)n * D + d0;
    const __bf16* pd = Db + (size_t)n * D + d0;
    float s1 = 0.f, s2 = 0.f;
#pragma unroll
    for (int u = 0; u < 16; ++u) {
        float a = (float)pa[u], c = (float)pc[u], b = (float)pB[u], dd = (float)pd[u];
        float vs_ = bs[d0 + u], vo_ = bo[d0 + u];
        s1 += a * c + a * vo_ + vs_ * c;
        s2 += b * dd + b * vo_ + vs_ * dd;
    }
    s1 = wave_reduce_sum(s1);
    s2 = wave_reduce_sum(s2);
    if (lane == 0) { nodeS[n] = s1; nodeO[n] = s2; }
}

__global__ __launch_bounds__(256) void edge_logits_kernel(
    const __bf16* __restrict__ rb, const float* __restrict__ P, const float* __restrict__ Q,
    const float* __restrict__ pb, const float* __restrict__ q,
    const float* __restrict__ nodeS, const float* __restrict__ nodeO,
    const float* __restrict__ G_AD, const float* __restrict__ G_BC,
    const int* __restrict__ sbj, const int* __restrict__ obj,
    float* __restrict__ logits, int E, int D, int Nn, float scale) {
    int e = blockIdx.x * 4 + (threadIdx.x >> 6);
    int lane = threadIdx.x & 63;
    int s = sbj[e], o = obj[e];
    int d0 = lane * 16;
    const __bf16* r = rb + (size_t)e * D + d0;
    const float* Ps = P + (size_t)s * D + d0;
    const float* Qo = Q + (size_t)o * D + d0;
    const float* Pb = pb + d0;
    float a = 0.f;
#pragma unroll
    for (int u = 0; u < 16; ++u) a += (float)r[u] * (Ps[u] + Qo[u] + Pb[u]);
    a = wave_reduce_sum(a);
    if (lane == 0) {
        float tot = a + q[e] + nodeS[s] + nodeO[o] +
                    G_AD[(size_t)s * Nn + o] + G_BC[(size_t)o * Nn + s];
        logits[e] = tot * scale;
    }
}

__global__ __launch_bounds__(256) void segmax_kernel(const float* __restrict__ logits,
                                                     const int* __restrict__ sbj,
                                                     const int* __restrict__ obj,
                                                     unsigned* __restrict__ mS,
                                                     unsigned* __restrict__ mO, int E) {
    int e = blockIdx.x * 256 + threadIdx.x;
    if (e >= E) return;
    unsigned k = fenc(logits[e]);
    atomicMax(mS + sbj[e], k);
    atomicMax(mO + obj[e], k);
}

__global__ __launch_bounds__(256) void expsum_kernel(const float* __restrict__ logits,
                                                     const int* __restrict__ sbj,
                                                     const int* __restrict__ obj,
                                                     const unsigned* __restrict__ mS,
                                                     const unsigned* __restrict__ mO,
                                                     float* __restrict__ es, float* __restrict__ eo,
                                                     float* __restrict__ sumS, float* __restrict__ sumO,
                                                     int E) {
    int e = blockIdx.x * 256 + threadIdx.x;
    if (e >= E) return;
    float l = logits[e];
    int s = sbj[e], o = obj[e];
    float a = expf(l - fdec(mS[s]));
    es[e] = a;
    atomicAdd(sumS + s, a);
    float b = expf(l - fdec(mO[o]));
    eo[e] = b;
    atomicAdd(sumO + o, b);
}

__global__ __launch_bounds__(256) void scatter_kernel(const float* __restrict__ es,
                                                      const float* __restrict__ eo,
                                                      const float* __restrict__ sumS,
                                                      const float* __restrict__ sumO,
                                                      const int* __restrict__ sbj,
                                                      const int* __restrict__ obj,
                                                      float* __restrict__ S, int* __restrict__ inv,
                                                      int E, int Nn) {
    int e = blockIdx.x * 256 + threadIdx.x;
    if (e >= E) return;
    int s = sbj[e], o = obj[e];
    atomicAdd(S + (size_t)s * Nn + o, es[e] / sumS[s]);
    atomicAdd(S + (size_t)o * Nn + s, eo[e] / sumO[o]);
    inv[s] = 1;
    inv[o] = 1;
}

// ---------------- host launcher ----------------

extern "C" void kernel_launch(void* const* d_in, const int* in_sizes, int n_in,
                              void* d_out, int out_size, void* d_ws, size_t ws_size,
                              hipStream_t stream) {
    const float* V     = (const float*)d_in[0];
    const float* relv  = (const float*)d_in[1];
    const float* W_rel = (const float*)d_in[2];
    const float* b_rel = (const float*)d_in[3];
    const float* W_sbj = (const float*)d_in[4];
    const float* b_sbj = (const float*)d_in[5];
    const float* W_obj = (const float*)d_in[6];
    const float* b_obj = (const float*)d_in[7];
    const float* W_ctx = (const float*)d_in[8];
    const float* b_ctx = (const float*)d_in[9];
    const int* sbj = (const int*)d_in[10];
    const int* obj = (const int*)d_in[11];

    const int D  = in_sizes[3];
    const int E  = in_sizes[10];
    const int Nn = in_sizes[12];
    const size_t DD = (size_t)D * D;

    const float* Wr_s = W_rel;
    const float* Wr_o = W_rel + DD;
    const float* Wr_r = W_rel + 2 * DD;
    const float* Ws_v = W_sbj;
    const float* Ws_r = W_sbj + DD;
    const float* Wo_v = W_obj;
    const float* Wo_r = W_obj + DD;

    char* ws = (char*)d_ws;
    size_t off = 0;
    auto alloc = [&](size_t bytes) -> void* {
        void* p = (void*)(ws + off);
        off += (bytes + 255) & ~(size_t)255;
        return p;
    };

    __bf16* relv_b  = (__bf16*)alloc((size_t)E * D * 2);
    __bf16* Vb      = (__bf16*)alloc((size_t)Nn * D * 2);
    __bf16* VbT     = (__bf16*)alloc((size_t)Nn * D * 2);
    __bf16* Wr_all  = (__bf16*)alloc(3 * DD * 2);
    __bf16* Ws_rT   = (__bf16*)alloc(DD * 2);
    __bf16* Wo_rT   = (__bf16*)alloc(DD * 2);
    __bf16* W_ctxT  = (__bf16*)alloc(DD * 2);
    __bf16* MsT     = (__bf16*)alloc(DD * 2);
    __bf16* MbT     = (__bf16*)alloc(DD * 2);
    __bf16* McT     = (__bf16*)alloc(DD * 2);
    __bf16* MdT     = (__bf16*)alloc(DD * 2);
    __bf16* Ks_b    = (__bf16*)alloc(DD * 2);
    __bf16* Ko_b    = (__bf16*)alloc(DD * 2);
    __bf16* ZT_b    = (__bf16*)alloc(DD * 2);
    __bf16* Ab      = (__bf16*)alloc((size_t)Nn * D * 2);
    __bf16* Bb      = (__bf16*)alloc((size_t)Nn * D * 2);
    __bf16* Cb      = (__bf16*)alloc((size_t)Nn * D * 2);
    __bf16* Db      = (__bf16*)alloc((size_t)Nn * D * 2);
    float* G_AD     = (float*)alloc((size_t)Nn * Nn * 4);
    float* G_BC     = (float*)alloc((size_t)Nn * Nn * 4);
    float* Pm       = (float*)alloc((size_t)Nn * D * 4);
    float* Qm       = (float*)alloc((size_t)Nn * D * 4);
    float* bs       = (float*)alloc((size_t)D * 4);
    float* bo       = (float*)alloc((size_t)D * 4);
    float* pb       = (float*)alloc((size_t)D * 4);
    float* nodeS    = (float*)alloc((size_t)Nn * 4);
    float* nodeO    = (float*)alloc((size_t)Nn * 4);
    float* logits   = (float*)alloc((size_t)E * 4);
    float* es       = (float*)alloc((size_t)E * 4);
    float* eo       = (float*)alloc((size_t)E * 4);
    size_t zbeg = off;
    float* S        = (float*)alloc((size_t)Nn * Nn * 4);
    float* q        = (float*)alloc((size_t)E * 4);
    unsigned* mS    = (unsigned*)alloc((size_t)Nn * 4);
    unsigned* mO    = (unsigned*)alloc((size_t)Nn * 4);
    float* sumS     = (float*)alloc((size_t)Nn * 4);
    float* sumO     = (float*)alloc((size_t)Nn * 4);
    int* inv        = (int*)alloc((size_t)Nn * 4);
    size_t zend = off;
    __bf16* Sb      = (__bf16*)alloc((size_t)Nn * Nn * 2);
    __bf16* ctx_b   = (__bf16*)alloc((size_t)Nn * D * 2);
    (void)ws_size; (void)n_in; (void)out_size;

    float* outVj = (float*)d_out + (size_t)E * D;

    // 1. passthrough output 0
    hipMemcpyAsync(d_out, relv, (size_t)E * D * 4, hipMemcpyDeviceToDevice, stream);
    // 2. zero atomic buffers
    hipMemsetAsync(ws + zbeg, 0, zend - zbeg, stream);

    // 3. conversions
    auto cvt = [&](const float* in, __bf16* out, size_t n) {
        int blocks = (int)((n / 4 + 255) / 256);
        cvt_f32_bf16<<<dim3(blocks), dim3(256), 0, stream>>>(in, out, (long long)n);
    };
    cvt(relv, relv_b, (size_t)E * D);
    cvt(W_rel, Wr_all, 3 * DD);
    cvt(V, Vb, (size_t)Nn * D);
    auto cvtT = [&](const float* in, __bf16* out, int R, int C) {
        cvt_t_bf16<<<dim3(C / 32, R / 32), dim3(256), 0, stream>>>(in, out, R, C);
    };
    cvtT(Ws_r, Ws_rT, D, D);
    cvtT(Wo_r, Wo_rT, D, D);
    cvtT(W_ctx, W_ctxT, D, D);
    cvtT(V, VbT, Nn, D);

    __bf16* Wr_s_b = Wr_all;
    __bf16* Wr_o_b = Wr_all + DD;
    __bf16* Wr_r_b = Wr_all + 2 * DD;

    // 4. bias projections
    beta_kernel<<<dim3((2 * D) / 256), dim3(256), 0, stream>>>(b_rel, b_sbj, b_obj, Ws_r, Wo_r, bs, bo, D);

    // 5. GEMM helper
    auto G = [&](int mode, const __bf16* A, const __bf16* Bt, int M, int N2, int K,
                 const float* addMat, float* outF, __bf16* outB, int accum,
                 const __bf16* rbD, float* qO, const float* addRow, const int* mask) {
        dim3 g(M / 64, N2 / 64), b(256);
        switch (mode) {
            case 0: gemm_bt<0><<<g, b, 0, stream>>>(A, Bt, M, N2, K, addMat, outF, outB, accum, rbD, qO, addRow, mask); break;
            case 1: gemm_bt<1><<<g, b, 0, stream>>>(A, Bt, M, N2, K, addMat, outF, outB, accum, rbD, qO, addRow, mask); break;
            case 2: gemm_bt<2><<<g, b, 0, stream>>>(A, Bt, M, N2, K, addMat, outF, outB, accum, rbD, qO, addRow, mask); break;
            case 3: gemm_bt<3><<<g, b, 0, stream>>>(A, Bt, M, N2, K, addMat, outF, outB, accum, rbD, qO, addRow, mask); break;
            case 4: gemm_bt<4><<<g, b, 0, stream>>>(A, Bt, M, N2, K, addMat, outF, outB, accum, rbD, qO, addRow, mask); break;
        }
    };

    // D^3 precomputes
    G(1, Wr_s_b, Ws_rT, D, D, D, Ws_v, nullptr, MsT, 0, nullptr, nullptr, nullptr, nullptr);
    G(1, Wr_o_b, Ws_rT, D, D, D, nullptr, nullptr, MbT, 0, nullptr, nullptr, nullptr, nullptr);
    G(1, Wr_s_b, Wo_rT, D, D, D, nullptr, nullptr, McT, 0, nullptr, nullptr, nullptr, nullptr);
    G(1, Wr_o_b, Wo_rT, D, D, D, Wo_v, nullptr, MdT, 0, nullptr, nullptr, nullptr, nullptr);
    G(0, Wr_r_b, Ws_rT, D, D, D, nullptr, nullptr, Ks_b, 0, nullptr, nullptr, nullptr, nullptr);
    G(0, Wr_r_b, Wo_rT, D, D, D, nullptr, nullptr, Ko_b, 0, nullptr, nullptr, nullptr, nullptr);
    G(0, Ko_b, Ks_b, D, D, D, nullptr, nullptr, ZT_b, 0, nullptr, nullptr, nullptr, nullptr);

    pbeta_kernel<<<dim3(D / 4), dim3(256), 0, stream>>>(bs, bo, Ks_b, Ko_b, pb, D);

    // N-side projections
    G(0, Vb, MsT, Nn, D, D, nullptr, nullptr, Ab, 0, nullptr, nullptr, nullptr, nullptr);
    G(0, Vb, MbT, Nn, D, D, nullptr, nullptr, Bb, 0, nullptr, nullptr, nullptr, nullptr);
    G(0, Vb, McT, Nn, D, D, nullptr, nullptr, Cb, 0, nullptr, nullptr, nullptr, nullptr);
    G(0, Vb, MdT, Nn, D, D, nullptr, nullptr, Db, 0, nullptr, nullptr, nullptr, nullptr);

    // Gram matrices + linear-term tables
    G(2, Ab, Db, Nn, Nn, D, nullptr, G_AD, nullptr, 0, nullptr, nullptr, nullptr, nullptr);
    G(2, Bb, Cb, Nn, Nn, D, nullptr, G_BC, nullptr, 0, nullptr, nullptr, nullptr, nullptr);
    G(2, Ab, Ko_b, Nn, D, D, nullptr, Pm, nullptr, 0, nullptr, nullptr, nullptr, nullptr);
    G(2, Cb, Ks_b, Nn, D, D, nullptr, Pm, nullptr, 1, nullptr, nullptr, nullptr, nullptr);
    G(2, Bb, Ko_b, Nn, D, D, nullptr, Qm, nullptr, 0, nullptr, nullptr, nullptr, nullptr);
    G(2, Db, Ks_b, Nn, D, D, nullptr, Qm, nullptr, 1, nullptr, nullptr, nullptr, nullptr);

    node_kernel<<<dim3(Nn / 4), dim3(256), 0, stream>>>(Ab, Cb, Bb, Db, bs, bo, nodeS, nodeO, Nn, D);

    // heavy: q[e] = (relv @ Z) . relv  (fused epilogue, never materializes Y)
    G(3, relv_b, ZT_b, E, D, D, nullptr, nullptr, nullptr, 0, relv_b, q, nullptr, nullptr);

    edge_logits_kernel<<<dim3(E / 4), dim3(256), 0, stream>>>(
        relv_b, Pm, Qm, pb, q, nodeS, nodeO, G_AD, G_BC, sbj, obj, logits, E, D, Nn,
        1.0f / sqrtf((float)D));

    segmax_kernel<<<dim3(E / 256), dim3(256), 0, stream>>>(logits, sbj, obj, mS, mO, E);
    expsum_kernel<<<dim3(E / 256), dim3(256), 0, stream>>>(logits, sbj, obj, mS, mO, es, eo, sumS, sumO, E);
    scatter_kernel<<<dim3(E / 256), dim3(256), 0, stream>>>(es, eo, sumS, sumO, sbj, obj, S, inv, E, Nn);

    cvt(S, Sb, (size_t)Nn * Nn);
    G(0, Sb, VbT, Nn, D, Nn, nullptr, nullptr, ctx_b, 0, nullptr, nullptr, nullptr, nullptr);
    G(4, ctx_b, W_ctxT, Nn, D, D, V, outVj, nullptr, 0, nullptr, nullptr, b_ctx, inv);
}

// Round 2
// 758.596 us; speedup vs baseline: 1.3038x; 1.3038x over previous
//
#include <hip/hip_runtime.h>
#include <hip/hip_bf16.h>
#include <math.h>

typedef __bf16 v8bf __attribute__((ext_vector_type(8)));
typedef __bf16 v4bf __attribute__((ext_vector_type(4)));
typedef float  v4f  __attribute__((ext_vector_type(4)));

__device__ __forceinline__ float wave_reduce_sum(float v) {
#pragma unroll
    for (int m = 1; m < 64; m <<= 1) v += __shfl_xor(v, m, 64);
    return v;
}

__device__ __forceinline__ unsigned fenc(float x) {
    unsigned u = __float_as_uint(x);
    return (u & 0x80000000u) ? ~u : (u | 0x80000000u);
}
__device__ __forceinline__ float fdec(unsigned k) {
    return (k & 0x80000000u) ? __uint_as_float(k ^ 0x80000000u) : __uint_as_float(~k);
}

// ---------------- conversion kernels ----------------

__global__ __launch_bounds__(256) void cvt_f32_bf16(const float* __restrict__ in,
                                                    __bf16* __restrict__ out, long long n) {
    long long i = ((long long)blockIdx.x * 256 + threadIdx.x) * 4;
    if (i >= n) return;
    v4f v = *(const v4f*)(in + i);
    v4bf o;
    o[0] = (__bf16)v[0]; o[1] = (__bf16)v[1]; o[2] = (__bf16)v[2]; o[3] = (__bf16)v[3];
    *(v4bf*)(out + i) = o;
}

// out[c][r] = (bf16) in[r][c];  R,C multiples of 32
__global__ __launch_bounds__(256) void cvt_t_bf16(const float* __restrict__ in,
                                                  __bf16* __restrict__ out, int R, int C) {
    __shared__ float tile[32][33];
    int cb = blockIdx.x * 32, rb = blockIdx.y * 32;
    int tx = threadIdx.x & 31, ty = threadIdx.x >> 5;  // ty in 0..7
#pragma unroll
    for (int i = 0; i < 32; i += 8)
        tile[ty + i][tx] = in[(size_t)(rb + ty + i) * C + cb + tx];
    __syncthreads();
#pragma unroll
    for (int i = 0; i < 32; i += 8)
        out[(size_t)(cb + ty + i) * R + rb + tx] = (__bf16)tile[tx][ty + i];
}

// ---------------- generic bf16 MFMA GEMM: out = A (MxK) @ Bt^T (Bt is NxK) ----------------
// MODE 0: outB (bf16, plain)  = acc (+addMat f32 if non-null)
// MODE 1: outB (bf16, TRANSPOSED write [n][m]) = acc (+addMat read plain [m][n])
// MODE 2: outF (f32, plain)   = acc (+= if accumFlag)
// MODE 3: fused row-dot: atomicAdd(qOut[m], sum_n acc[m][n]*rbDot[m][n])
// MODE 4: outF[m][n] = addMat[m][n] + (maskRow[m] ? acc + addRow[n] : 0)
template <int MODE>
__global__ __launch_bounds__(256) void gemm_bt(
    const __bf16* __restrict__ Ap, const __bf16* __restrict__ Btp,
    int M, int N, int K,
    const float* __restrict__ addMat,
    float* __restrict__ outF,
    __bf16* __restrict__ outB,
    int accumFlag,
    const __bf16* __restrict__ rbDot,
    float* __restrict__ qOut,
    const float* __restrict__ addRow,
    const int* __restrict__ maskRow) {
    __shared__ alignas(16) __bf16 As[64][72];
    __shared__ alignas(16) __bf16 Bs[64][72];
    const int m0 = blockIdx.x * 64, n0 = blockIdx.y * 64;
    const int t = threadIdx.x;
    const int lane = t & 63, wid = t >> 6;
    const int wm = wid >> 1, wn = wid & 1;
    v4f acc[2][2] = {};

    for (int kt = 0; kt < K; kt += 64) {
#pragma unroll
        for (int s2 = 0; s2 < 2; ++s2) {
            int c = t + s2 * 256;
            int row = c >> 3, ch = c & 7;
            *(v8bf*)&As[row][ch * 8] = *(const v8bf*)(Ap + (size_t)(m0 + row) * K + kt + ch * 8);
            *(v8bf*)&Bs[row][ch * 8] = *(const v8bf*)(Btp + (size_t)(n0 + row) * K + kt + ch * 8);
        }
        __syncthreads();
#pragma unroll
        for (int ks = 0; ks < 2; ++ks) {
            const int kl = ks * 32 + ((lane >> 4) << 3);
            v8bf af[2], bfr[2];
#pragma unroll
            for (int f = 0; f < 2; ++f) {
                af[f]  = *(const v8bf*)&As[wm * 32 + f * 16 + (lane & 15)][kl];
                bfr[f] = *(const v8bf*)&Bs[wn * 32 + f * 16 + (lane & 15)][kl];
            }
#pragma unroll
            for (int i = 0; i < 2; ++i)
#pragma unroll
                for (int j = 0; j < 2; ++j)
                    acc[i][j] = __builtin_amdgcn_mfma_f32_16x16x32_bf16(af[i], bfr[j], acc[i][j], 0, 0, 0);
        }
        __syncthreads();
    }

    const int cc = lane & 15, r4 = (lane >> 4) << 2;
    if constexpr (MODE == 3) {
#pragma unroll
        for (int i = 0; i < 2; ++i)
#pragma unroll
            for (int r = 0; r < 4; ++r) {
                const int gm = m0 + wm * 32 + i * 16 + r4 + r;
                float p = 0.f;
#pragma unroll
                for (int j = 0; j < 2; ++j) {
                    const int gn = n0 + wn * 32 + j * 16 + cc;
                    p += acc[i][j][r] * (float)rbDot[(size_t)gm * N + gn];
                }
                p += __shfl_xor(p, 1, 64);
                p += __shfl_xor(p, 2, 64);
                p += __shfl_xor(p, 4, 64);
                p += __shfl_xor(p, 8, 64);
                if (cc == 0) atomicAdd(qOut + gm, p);
            }
    } else {
#pragma unroll
        for (int i = 0; i < 2; ++i)
#pragma unroll
            for (int j = 0; j < 2; ++j)
#pragma unroll
                for (int r = 0; r < 4; ++r) {
                    const int gm = m0 + wm * 32 + i * 16 + r4 + r;
                    const int gn = n0 + wn * 32 + j * 16 + cc;
                    float v = acc[i][j][r];
                    if constexpr (MODE == 0) {
                        if (addMat) v += addMat[(size_t)gm * N + gn];
                        outB[(size_t)gm * N + gn] = (__bf16)v;
                    } else if constexpr (MODE == 1) {
                        if (addMat) v += addMat[(size_t)gm * N + gn];
                        outB[(size_t)gn * M + gm] = (__bf16)v;
                    } else if constexpr (MODE == 2) {
                        if (accumFlag) v += outF[(size_t)gm * N + gn];
                        outF[(size_t)gm * N + gn] = v;
                    } else {  // MODE 4
                        float u = addMat[(size_t)gm * N + gn];
                        if (maskRow[gm]) u += v + addRow[gn];
                        outF[(size_t)gm * N + gn] = u;
                    }
                }
    }
}

// ---------------- small custom kernels ----------------

// bs = b_sbj + b_rel @ Ws_r ; bo = b_obj + b_rel @ Wo_r
// Two-stage: grid (D/256 cols, 32 row-chunks, 2 matrices); coalesced row-major
// reads; atomicAdd partials into zero-initialized bs/bo. The y==0 block folds
// in the bias vector.
__global__ __launch_bounds__(256) void beta_kernel(
    const float* __restrict__ b_rel, const float* __restrict__ b_sbj, const float* __restrict__ b_obj,
    const float* __restrict__ Wsr, const float* __restrict__ Wor,
    float* __restrict__ bs, float* __restrict__ bo, int D, int rowsPerChunk) {
    const int col = blockIdx.x * 256 + threadIdx.x;
    if (col >= D) return;
    const int r0 = blockIdx.y * rowsPerChunk;
    const float* W = (blockIdx.z == 0) ? Wsr : Wor;
    float acc = 0.f;
    if (blockIdx.y == 0) acc = (blockIdx.z == 0) ? b_sbj[col] : b_obj[col];
    const int rEnd = min(r0 + rowsPerChunk, D);
    for (int r = r0; r < rEnd; ++r)
        acc += b_rel[r] * W[(size_t)r * D + col];
    float* out = (blockIdx.z == 0) ? bs : bo;
    atomicAdd(out + col, acc);
}

__global__ __launch_bounds__(256) void pbeta_kernel(const float* __restrict__ bs,
                                                    const float* __restrict__ bo,
                                                    const __bf16* __restrict__ Ks,
                                                    const __bf16* __restrict__ Ko,
                                                    float* __restrict__ pb, int D) {
    int d = blockIdx.x * 4 + (threadIdx.x >> 6);
    int lane = threadIdx.x & 63;
    float a = 0.f;
    for (int j = lane; j < D; j += 64)
        a += bs[j] * (float)Ko[(size_t)d * D + j] + bo[j] * (float)Ks[(size_t)d * D + j];
    a = wave_reduce_sum(a);
    if (lane == 0) pb[d] = a;
}

__global__ __launch_bounds__(256) void node_kernel(
    const __bf16* __restrict__ Ab, const __bf16* __restrict__ Cb,
    const __bf16* __restrict__ Bb, const __bf16* __restrict__ Db,
    const float* __restrict__ bs, const float* __restrict__ bo,
    float* __restrict__ nodeS, float* __restrict__ nodeO, int Nn, int D) {
    int n = blockIdx.x * 4 + (threadIdx.x >> 6);
    int lane = threadIdx.x & 63;
    int d0 = lane * 16;
    const __bf16* pa = Ab + (size_t)n * D + d0;
    const __bf16* pc = Cb + (size_t)n * D + d0;
    const __bf16* pB = Bb + (size_t)n * D + d0;
    const __bf16* pd = Db + (size_t)n * D + d0;
    float s1 = 0.f, s2 = 0.f;
#pragma unroll
    for (int u = 0; u < 16; ++u) {
        float a = (float)pa[u], c = (float)pc[u], b = (float)pB[u], dd = (float)pd[u];
        float vs_ = bs[d0 + u], vo_ = bo[d0 + u];
        s1 += a * c + a * vo_ + vs_ * c;
        s2 += b * dd + b * vo_ + vs_ * dd;
    }
    s1 = wave_reduce_sum(s1);
    s2 = wave_reduce_sum(s2);
    if (lane == 0) { nodeS[n] = s1; nodeO[n] = s2; }
}

__global__ __launch_bounds__(256) void edge_logits_kernel(
    const __bf16* __restrict__ rb, const float* __restrict__ P, const float* __restrict__ Q,
    const float* __restrict__ pb, const float* __restrict__ q,
    const float* __restrict__ nodeS, const float* __restrict__ nodeO,
    const float* __restrict__ G_AD, const float* __restrict__ G_BC,
    const int* __restrict__ sbj, const int* __restrict__ obj,
    float* __restrict__ logits, int E, int D, int Nn, float scale) {
    int e = blockIdx.x * 4 + (threadIdx.x >> 6);
    int lane = threadIdx.x & 63;
    int s = sbj[e], o = obj[e];
    int d0 = lane * 16;
    const __bf16* r = rb + (size_t)e * D + d0;
    const float* Ps = P + (size_t)s * D + d0;
    const float* Qo = Q + (size_t)o * D + d0;
    const float* Pb = pb + d0;
    float a = 0.f;
#pragma unroll
    for (int u = 0; u < 16; ++u) a += (float)r[u] * (Ps[u] + Qo[u] + Pb[u]);
    a = wave_reduce_sum(a);
    if (lane == 0) {
        float tot = a + q[e] + nodeS[s] + nodeO[o] +
                    G_AD[(size_t)s * Nn + o] + G_BC[(size_t)o * Nn + s];
        logits[e] = tot * scale;
    }
}

__global__ __launch_bounds__(256) void segmax_kernel(const float* __restrict__ logits,
                                                     const int* __restrict__ sbj,
                                                     const int* __restrict__ obj,
                                                     unsigned* __restrict__ mS,
                                                     unsigned* __restrict__ mO, int E) {
    int e = blockIdx.x * 256 + threadIdx.x;
    if (e >= E) return;
    unsigned k = fenc(logits[e]);
    atomicMax(mS + sbj[e], k);
    atomicMax(mO + obj[e], k);
}

__global__ __launch_bounds__(256) void expsum_kernel(const float* __restrict__ logits,
                                                     const int* __restrict__ sbj,
                                                     const int* __restrict__ obj,
                                                     const unsigned* __restrict__ mS,
                                                     const unsigned* __restrict__ mO,
                                                     float* __restrict__ es, float* __restrict__ eo,
                                                     float* __restrict__ sumS, float* __restrict__ sumO,
                                                     int E) {
    int e = blockIdx.x * 256 + threadIdx.x;
    if (e >= E) return;
    float l = logits[e];
    int s = sbj[e], o = obj[e];
    float a = expf(l - fdec(mS[s]));
    es[e] = a;
    atomicAdd(sumS + s, a);
    float b = expf(l - fdec(mO[o]));
    eo[e] = b;
    atomicAdd(sumO + o, b);
}

__global__ __launch_bounds__(256) void scatter_kernel(const float* __restrict__ es,
                                                      const float* __restrict__ eo,
                                                      const float* __restrict__ sumS,
                                                      const float* __restrict__ sumO,
                                                      const int* __restrict__ sbj,
                                                      const int* __restrict__ obj,
                                                      float* __restrict__ S, int* __restrict__ inv,
                                                      int E, int Nn) {
    int e = blockIdx.x * 256 + threadIdx.x;
    if (e >= E) return;
    int s = sbj[e], o = obj[e];
    atomicAdd(S + (size_t)s * Nn + o, es[e] / sumS[s]);
    atomicAdd(S + (size_t)o * Nn + s, eo[e] / sumO[o]);
    inv[s] = 1;
    inv[o] = 1;
}

// ---------------- host launcher ----------------

extern "C" void kernel_launch(void* const* d_in, const int* in_sizes, int n_in,
                              void* d_out, int out_size, void* d_ws, size_t ws_size,
                              hipStream_t stream) {
    const float* V     = (const float*)d_in[0];
    const float* relv  = (const float*)d_in[1];
    const float* W_rel = (const float*)d_in[2];
    const float* b_rel = (const float*)d_in[3];
    const float* W_sbj = (const float*)d_in[4];
    const float* b_sbj = (const float*)d_in[5];
    const float* W_obj = (const float*)d_in[6];
    const float* b_obj = (const float*)d_in[7];
    const float* W_ctx = (const float*)d_in[8];
    const float* b_ctx = (const float*)d_in[9];
    const int* sbj = (const int*)d_in[10];
    const int* obj = (const int*)d_in[11];

    const int D  = in_sizes[3];
    const int E  = in_sizes[10];
    const int Nn = in_sizes[12];
    const size_t DD = (size_t)D * D;

    const float* Wr_s = W_rel;
    const float* Wr_o = W_rel + DD;
    const float* Wr_r = W_rel + 2 * DD;
    const float* Ws_v = W_sbj;
    const float* Ws_r = W_sbj + DD;
    const float* Wo_v = W_obj;
    const float* Wo_r = W_obj + DD;

    char* ws = (char*)d_ws;
    size_t off = 0;
    auto alloc = [&](size_t bytes) -> void* {
        void* p = (void*)(ws + off);
        off += (bytes + 255) & ~(size_t)255;
        return p;
    };

    __bf16* relv_b  = (__bf16*)alloc((size_t)E * D * 2);
    __bf16* Vb      = (__bf16*)alloc((size_t)Nn * D * 2);
    __bf16* VbT     = (__bf16*)alloc((size_t)Nn * D * 2);
    __bf16* Wr_all  = (__bf16*)alloc(3 * DD * 2);
    __bf16* Ws_rT   = (__bf16*)alloc(DD * 2);
    __bf16* Wo_rT   = (__bf16*)alloc(DD * 2);
    __bf16* W_ctxT  = (__bf16*)alloc(DD * 2);
    __bf16* MsT     = (__bf16*)alloc(DD * 2);
    __bf16* MbT     = (__bf16*)alloc(DD * 2);
    __bf16* McT     = (__bf16*)alloc(DD * 2);
    __bf16* MdT     = (__bf16*)alloc(DD * 2);
    __bf16* Ks_b    = (__bf16*)alloc(DD * 2);
    __bf16* Ko_b    = (__bf16*)alloc(DD * 2);
    __bf16* ZT_b    = (__bf16*)alloc(DD * 2);
    __bf16* Ab      = (__bf16*)alloc((size_t)Nn * D * 2);
    __bf16* Bb      = (__bf16*)alloc((size_t)Nn * D * 2);
    __bf16* Cb      = (__bf16*)alloc((size_t)Nn * D * 2);
    __bf16* Db      = (__bf16*)alloc((size_t)Nn * D * 2);
    float* G_AD     = (float*)alloc((size_t)Nn * Nn * 4);
    float* G_BC     = (float*)alloc((size_t)Nn * Nn * 4);
    float* Pm       = (float*)alloc((size_t)Nn * D * 4);
    float* Qm       = (float*)alloc((size_t)Nn * D * 4);
    float* pb       = (float*)alloc((size_t)D * 4);
    float* nodeS    = (float*)alloc((size_t)Nn * 4);
    float* nodeO    = (float*)alloc((size_t)Nn * 4);
    float* logits   = (float*)alloc((size_t)E * 4);
    float* es       = (float*)alloc((size_t)E * 4);
    float* eo       = (float*)alloc((size_t)E * 4);
    size_t zbeg = off;
    float* S        = (float*)alloc((size_t)Nn * Nn * 4);
    float* q        = (float*)alloc((size_t)E * 4);
    float* bs       = (float*)alloc((size_t)D * 4);
    float* bo       = (float*)alloc((size_t)D * 4);
    unsigned* mS    = (unsigned*)alloc((size_t)Nn * 4);
    unsigned* mO    = (unsigned*)alloc((size_t)Nn * 4);
    float* sumS     = (float*)alloc((size_t)Nn * 4);
    float* sumO     = (float*)alloc((size_t)Nn * 4);
    int* inv        = (int*)alloc((size_t)Nn * 4);
    size_t zend = off;
    __bf16* Sb      = (__bf16*)alloc((size_t)Nn * Nn * 2);
    __bf16* ctx_b   = (__bf16*)alloc((size_t)Nn * D * 2);
    (void)ws_size; (void)n_in; (void)out_size;

    float* outVj = (float*)d_out + (size_t)E * D;

    // 1. passthrough output 0
    hipMemcpyAsync(d_out, relv, (size_t)E * D * 4, hipMemcpyDeviceToDevice, stream);
    // 2. zero atomic buffers (includes bs/bo accumulated by beta_kernel)
    hipMemsetAsync(ws + zbeg, 0, zend - zbeg, stream);

    // 3. conversions
    auto cvt = [&](const float* in, __bf16* out, size_t n) {
        int blocks = (int)((n / 4 + 255) / 256);
        cvt_f32_bf16<<<dim3(blocks), dim3(256), 0, stream>>>(in, out, (long long)n);
    };
    cvt(relv, relv_b, (size_t)E * D);
    cvt(W_rel, Wr_all, 3 * DD);
    cvt(V, Vb, (size_t)Nn * D);
    auto cvtT = [&](const float* in, __bf16* out, int R, int C) {
        cvt_t_bf16<<<dim3(C / 32, R / 32), dim3(256), 0, stream>>>(in, out, R, C);
    };
    cvtT(Ws_r, Ws_rT, D, D);
    cvtT(Wo_r, Wo_rT, D, D);
    cvtT(W_ctx, W_ctxT, D, D);
    cvtT(V, VbT, Nn, D);

    __bf16* Wr_s_b = Wr_all;
    __bf16* Wr_o_b = Wr_all + DD;
    __bf16* Wr_r_b = Wr_all + 2 * DD;

    // 4. bias projections: parallel 2-stage reduce, coalesced, 256 blocks
    {
        int colBlocks = (D + 255) / 256;
        int rowChunks = 32;
        int rowsPerChunk = (D + rowChunks - 1) / rowChunks;
        beta_kernel<<<dim3(colBlocks, rowChunks, 2), dim3(256), 0, stream>>>(
            b_rel, b_sbj, b_obj, Ws_r, Wo_r, bs, bo, D, rowsPerChunk);
    }

    // 5. GEMM helper
    auto G = [&](int mode, const __bf16* A, const __bf16* Bt, int M, int N2, int K,
                 const float* addMat, float* outF, __bf16* outB, int accum,
                 const __bf16* rbD, float* qO, const float* addRow, const int* mask) {
        dim3 g(M / 64, N2 / 64), b(256);
        switch (mode) {
            case 0: gemm_bt<0><<<g, b, 0, stream>>>(A, Bt, M, N2, K, addMat, outF, outB, accum, rbD, qO, addRow, mask); break;
            case 1: gemm_bt<1><<<g, b, 0, stream>>>(A, Bt, M, N2, K, addMat, outF, outB, accum, rbD, qO, addRow, mask); break;
            case 2: gemm_bt<2><<<g, b, 0, stream>>>(A, Bt, M, N2, K, addMat, outF, outB, accum, rbD, qO, addRow, mask); break;
            case 3: gemm_bt<3><<<g, b, 0, stream>>>(A, Bt, M, N2, K, addMat, outF, outB, accum, rbD, qO, addRow, mask); break;
            case 4: gemm_bt<4><<<g, b, 0, stream>>>(A, Bt, M, N2, K, addMat, outF, outB, accum, rbD, qO, addRow, mask); break;
        }
    };

    // D^3 precomputes
    G(1, Wr_s_b, Ws_rT, D, D, D, Ws_v, nullptr, MsT, 0, nullptr, nullptr, nullptr, nullptr);
    G(1, Wr_o_b, Ws_rT, D, D, D, nullptr, nullptr, MbT, 0, nullptr, nullptr, nullptr, nullptr);
    G(1, Wr_s_b, Wo_rT, D, D, D, nullptr, nullptr, McT, 0, nullptr, nullptr, nullptr, nullptr);
    G(1, Wr_o_b, Wo_rT, D, D, D, Wo_v, nullptr, MdT, 0, nullptr, nullptr, nullptr, nullptr);
    G(0, Wr_r_b, Ws_rT, D, D, D, nullptr, nullptr, Ks_b, 0, nullptr, nullptr, nullptr, nullptr);
    G(0, Wr_r_b, Wo_rT, D, D, D, nullptr, nullptr, Ko_b, 0, nullptr, nullptr, nullptr, nullptr);
    G(0, Ko_b, Ks_b, D, D, D, nullptr, nullptr, ZT_b, 0, nullptr, nullptr, nullptr, nullptr);

    pbeta_kernel<<<dim3(D / 4), dim3(256), 0, stream>>>(bs, bo, Ks_b, Ko_b, pb, D);

    // N-side projections
    G(0, Vb, MsT, Nn, D, D, nullptr, nullptr, Ab, 0, nullptr, nullptr, nullptr, nullptr);
    G(0, Vb, MbT, Nn, D, D, nullptr, nullptr, Bb, 0, nullptr, nullptr, nullptr, nullptr);
    G(0, Vb, McT, Nn, D, D, nullptr, nullptr, Cb, 0, nullptr, nullptr, nullptr, nullptr);
    G(0, Vb, MdT, Nn, D, D, nullptr, nullptr, Db, 0, nullptr, nullptr, nullptr, nullptr);

    // Gram matrices + linear-term tables
    G(2, Ab, Db, Nn, Nn, D, nullptr, G_AD, nullptr, 0, nullptr, nullptr, nullptr, nullptr);
    G(2, Bb, Cb, Nn, Nn, D, nullptr, G_BC, nullptr, 0, nullptr, nullptr, nullptr, nullptr);
    G(2, Ab, Ko_b, Nn, D, D, nullptr, Pm, nullptr, 0, nullptr, nullptr, nullptr, nullptr);
    G(2, Cb, Ks_b, Nn, D, D, nullptr, Pm, nullptr, 1, nullptr, nullptr, nullptr, nullptr);
    G(2, Bb, Ko_b, Nn, D, D, nullptr, Qm, nullptr, 0, nullptr, nullptr, nullptr, nullptr);
    G(2, Db, Ks_b, Nn, D, D, nullptr, Qm, nullptr, 1, nullptr, nullptr, nullptr, nullptr);

    node_kernel<<<dim3(Nn / 4), dim3(256), 0, stream>>>(Ab, Cb, Bb, Db, bs, bo, nodeS, nodeO, Nn, D);

    // heavy: q[e] = (relv @ Z) . relv  (fused epilogue, never materializes Y)
    G(3, relv_b, ZT_b, E, D, D, nullptr, nullptr, nullptr, 0, relv_b, q, nullptr, nullptr);

    edge_logits_kernel<<<dim3(E / 4), dim3(256), 0, stream>>>(
        relv_b, Pm, Qm, pb, q, nodeS, nodeO, G_AD, G_BC, sbj, obj, logits, E, D, Nn,
        1.0f / sqrtf((float)D));

    segmax_kernel<<<dim3(E / 256), dim3(256), 0, stream>>>(logits, sbj, obj, mS, mO, E);
    expsum_kernel<<<dim3(E / 256), dim3(256), 0, stream>>>(logits, sbj, obj, mS, mO, es, eo, sumS, sumO, E);
    scatter_kernel<<<dim3(E / 256), dim3(256), 0, stream>>>(es, eo, sumS, sumO, sbj, obj, S, inv, E, Nn);

    cvt(S, Sb, (size_t)Nn * Nn);
    G(0, Sb, VbT, Nn, D, Nn, nullptr, nullptr, ctx_b, 0, nullptr, nullptr, nullptr, nullptr);
    G(4, ctx_b, W_ctxT, Nn, D, Nn == 0 ? D : D, V, outVj, nullptr, 0, nullptr, nullptr, b_ctx, inv);
}

// Round 3
// 533.256 us; speedup vs baseline: 1.8548x; 1.4226x over previous
//
#include <hip/hip_runtime.h>
#include <hip/hip_bf16.h>
#include <math.h>

typedef __bf16 v8bf __attribute__((ext_vector_type(8)));
typedef __bf16 v4bf __attribute__((ext_vector_type(4)));
typedef float  v4f  __attribute__((ext_vector_type(4)));

__device__ __forceinline__ float wave_reduce_sum(float v) {
#pragma unroll
    for (int m = 1; m < 64; m <<= 1) v += __shfl_xor(v, m, 64);
    return v;
}

__device__ __forceinline__ unsigned fenc(float x) {
    unsigned u = __float_as_uint(x);
    return (u & 0x80000000u) ? ~u : (u | 0x80000000u);
}
__device__ __forceinline__ float fdec(unsigned k) {
    return (k & 0x80000000u) ? __uint_as_float(k ^ 0x80000000u) : __uint_as_float(~k);
}

__device__ __forceinline__ void gload16(const void* g, void* l) {
    __builtin_amdgcn_global_load_lds((const __attribute__((address_space(1))) void*)g,
                                     (__attribute__((address_space(3))) void*)l, 16, 0, 0);
}

// ---------------- conversion kernels ----------------

__global__ __launch_bounds__(256) void cvt_f32_bf16(const float* __restrict__ in,
                                                    __bf16* __restrict__ out, long long n) {
    long long i = ((long long)blockIdx.x * 256 + threadIdx.x) * 4;
    if (i >= n) return;
    v4f v = *(const v4f*)(in + i);
    v4bf o;
    o[0] = (__bf16)v[0]; o[1] = (__bf16)v[1]; o[2] = (__bf16)v[2]; o[3] = (__bf16)v[3];
    *(v4bf*)(out + i) = o;
}

// out[c][r] = (bf16) in[r][c];  R,C multiples of 32
__global__ __launch_bounds__(256) void cvt_t_bf16(const float* __restrict__ in,
                                                  __bf16* __restrict__ out, int R, int C) {
    __shared__ float tile[32][33];
    int cb = blockIdx.x * 32, rb = blockIdx.y * 32;
    int tx = threadIdx.x & 31, ty = threadIdx.x >> 5;  // ty in 0..7
#pragma unroll
    for (int i = 0; i < 32; i += 8)
        tile[ty + i][tx] = in[(size_t)(rb + ty + i) * C + cb + tx];
    __syncthreads();
#pragma unroll
    for (int i = 0; i < 32; i += 8)
        out[(size_t)(cb + ty + i) * R + rb + tx] = (__bf16)tile[tx][ty + i];
}

// ---- bf16 MFMA GEMM, m97 structure: global_load_lds(16B) staging, BK=64 ----
// out = A (MxK, ldA) @ Bt^T (Bt is NxK, ldB)
// MODE 0: outB (bf16, plain, ldOut)        = acc (+addMat f32 [ldAdd] if non-null)
// MODE 1: outB (bf16, transposed [n][m], ldOut) = acc (+addMat [m][n])
// MODE 2: outF (f32, plain, ldOut)         = acc
// MODE 3: fused row-dot: atomicAdd(qOut[m], sum_n acc[m][n]*rbDot[m][n])  (rbDot ld = N)
// MODE 4: outF[m][n] = addMat[m][n] + (maskRow[m] ? acc + addRow[n] : 0)
template <int MODE, bool BIG>
__global__ __launch_bounds__(256) void gemm_gl(
    const __bf16* __restrict__ Ap, int ldA,
    const __bf16* __restrict__ Btp, int ldB,
    int M, int N, int K,
    const float* __restrict__ addMat, int ldAdd,
    float* __restrict__ outF,
    __bf16* __restrict__ outB, int ldOut,
    const __bf16* __restrict__ rbDot,
    float* __restrict__ qOut,
    const float* __restrict__ addRow,
    const int* __restrict__ maskRow) {
    constexpr int BM = BIG ? 128 : 64;
    constexpr int BN = BIG ? 128 : 64;
    constexpr int WM = BM / 2, WN = BN / 2;       // per-wave output tile (2x2 waves)
    constexpr int FI = WM / 16, FJ = WN / 16;
    constexpr int NLA = (BM * 64) / 2048;         // global_load_lds instrs per tile (256 thr x 16B)
    constexpr int NLB = (BN * 64) / 2048;

    __shared__ alignas(16) __bf16 As[BM * 64];
    __shared__ alignas(16) __bf16 Bs[BN * 64];

    const int m0 = blockIdx.x * BM, n0 = blockIdx.y * BN;
    const int t = threadIdx.x, lane = t & 63, wid = t >> 6;
    const int wm = wid >> 1, wn = wid & 1;
    const int rA = t >> 3, cA = t & 7;            // 8 threads per 64-col row, 16B each

    v4f acc[FI][FJ] = {};

    for (int kt = 0; kt < K; kt += 64) {
#pragma unroll
        for (int i = 0; i < NLA; ++i)
            gload16(Ap + (size_t)(m0 + i * 32 + rA) * ldA + kt + cA * 8,
                    (char*)As + i * 4096 + wid * 1024);
#pragma unroll
        for (int i = 0; i < NLB; ++i)
            gload16(Btp + (size_t)(n0 + i * 32 + rA) * ldB + kt + cA * 8,
                    (char*)Bs + i * 4096 + wid * 1024);
        __syncthreads();
#pragma unroll
        for (int ks = 0; ks < 2; ++ks) {
            const int kb = ks * 64 + ((lane >> 4) << 4);  // byte offset within 128B row
            v8bf af[FI], bfr[FJ];
#pragma unroll
            for (int f = 0; f < FI; ++f)
                af[f] = *(const v8bf*)((const char*)As + (wm * WM + f * 16 + (lane & 15)) * 128 + kb);
#pragma unroll
            for (int f = 0; f < FJ; ++f)
                bfr[f] = *(const v8bf*)((const char*)Bs + (wn * WN + f * 16 + (lane & 15)) * 128 + kb);
#pragma unroll
            for (int i = 0; i < FI; ++i)
#pragma unroll
                for (int j = 0; j < FJ; ++j)
                    acc[i][j] = __builtin_amdgcn_mfma_f32_16x16x32_bf16(af[i], bfr[j], acc[i][j], 0, 0, 0);
        }
        __syncthreads();
    }

    const int cc = lane & 15, r4 = (lane >> 4) << 2;
    if constexpr (MODE == 3) {
#pragma unroll
        for (int i = 0; i < FI; ++i)
#pragma unroll
            for (int r = 0; r < 4; ++r) {
                const int gm = m0 + wm * WM + i * 16 + r4 + r;
                float p = 0.f;
#pragma unroll
                for (int j = 0; j < FJ; ++j) {
                    const int gn = n0 + wn * WN + j * 16 + cc;
                    p += acc[i][j][r] * (float)rbDot[(size_t)gm * N + gn];
                }
                p += __shfl_xor(p, 1, 64);
                p += __shfl_xor(p, 2, 64);
                p += __shfl_xor(p, 4, 64);
                p += __shfl_xor(p, 8, 64);
                if (cc == 0) atomicAdd(qOut + gm, p);
            }
    } else {
#pragma unroll
        for (int i = 0; i < FI; ++i)
#pragma unroll
            for (int j = 0; j < FJ; ++j)
#pragma unroll
                for (int r = 0; r < 4; ++r) {
                    const int gm = m0 + wm * WM + i * 16 + r4 + r;
                    const int gn = n0 + wn * WN + j * 16 + cc;
                    float v = acc[i][j][r];
                    if constexpr (MODE == 0) {
                        if (addMat) v += addMat[(size_t)gm * ldAdd + gn];
                        outB[(size_t)gm * ldOut + gn] = (__bf16)v;
                    } else if constexpr (MODE == 1) {
                        if (addMat) v += addMat[(size_t)gm * ldAdd + gn];
                        outB[(size_t)gn * ldOut + gm] = (__bf16)v;
                    } else if constexpr (MODE == 2) {
                        outF[(size_t)gm * ldOut + gn] = v;
                    } else {  // MODE 4
                        float u = addMat[(size_t)gm * ldAdd + gn];
                        if (maskRow[gm]) u += v + addRow[gn];
                        outF[(size_t)gm * ldOut + gn] = u;
                    }
                }
    }
}

// ---------------- small custom kernels ----------------

// bs = b_sbj + b_rel @ Ws_r ; bo = b_obj + b_rel @ Wo_r  (into zeroed bs/bo)
__global__ __launch_bounds__(256) void beta_kernel(
    const float* __restrict__ b_rel, const float* __restrict__ b_sbj, const float* __restrict__ b_obj,
    const float* __restrict__ Wsr, const float* __restrict__ Wor,
    float* __restrict__ bs, float* __restrict__ bo, int D, int rowsPerChunk) {
    const int col = blockIdx.x * 256 + threadIdx.x;
    if (col >= D) return;
    const int r0 = blockIdx.y * rowsPerChunk;
    const float* W = (blockIdx.z == 0) ? Wsr : Wor;
    float acc = 0.f;
    if (blockIdx.y == 0) acc = (blockIdx.z == 0) ? b_sbj[col] : b_obj[col];
    const int rEnd = min(r0 + rowsPerChunk, D);
    for (int r = r0; r < rEnd; ++r)
        acc += b_rel[r] * W[(size_t)r * D + col];
    float* out = (blockIdx.z == 0) ? bs : bo;
    atomicAdd(out + col, acc);
}

// pb[d] = sum_j bs[j]*Ko[d][j] + bo[j]*Ks[d][j];  KoKs = [D][2048] = [Ko | Ks]
__global__ __launch_bounds__(256) void pbeta_kernel(const float* __restrict__ bs,
                                                    const float* __restrict__ bo,
                                                    const __bf16* __restrict__ KoKs,
                                                    float* __restrict__ pb, int D) {
    int d = blockIdx.x * 4 + (threadIdx.x >> 6);
    int lane = threadIdx.x & 63;
    float a = 0.f;
    for (int j = lane; j < D; j += 64)
        a += bs[j] * (float)KoKs[(size_t)d * 2048 + j] + bo[j] * (float)KoKs[(size_t)d * 2048 + 1024 + j];
    a = wave_reduce_sum(a);
    if (lane == 0) pb[d] = a;
}

// ACBD = [A | C | B | D] row blocks of width D, ld = 4D
__global__ __launch_bounds__(256) void node_kernel(
    const __bf16* __restrict__ ACBD,
    const float* __restrict__ bs, const float* __restrict__ bo,
    float* __restrict__ nodeS, float* __restrict__ nodeO, int D) {
    int n = blockIdx.x * 4 + (threadIdx.x >> 6);
    int lane = threadIdx.x & 63;
    int d0 = lane * 16;
    const __bf16* row = ACBD + (size_t)n * 4 * D;
    const __bf16* pa = row + d0;
    const __bf16* pc = row + D + d0;
    const __bf16* pB = row + 2 * D + d0;
    const __bf16* pd = row + 3 * D + d0;
    float s1 = 0.f, s2 = 0.f;
#pragma unroll
    for (int u = 0; u < 16; ++u) {
        float a = (float)pa[u], c = (float)pc[u], b = (float)pB[u], dd = (float)pd[u];
        float vs_ = bs[d0 + u], vo_ = bo[d0 + u];
        s1 += a * c + a * vo_ + vs_ * c;
        s2 += b * dd + b * vo_ + vs_ * dd;
    }
    s1 = wave_reduce_sum(s1);
    s2 = wave_reduce_sum(s2);
    if (lane == 0) { nodeS[n] = s1; nodeO[n] = s2; }
}

__global__ __launch_bounds__(256) void edge_logits_kernel(
    const __bf16* __restrict__ rb, const float* __restrict__ P, const float* __restrict__ Q,
    const float* __restrict__ pb, const float* __restrict__ q,
    const float* __restrict__ nodeS, const float* __restrict__ nodeO,
    const float* __restrict__ G_AD, const float* __restrict__ G_BC,
    const int* __restrict__ sbj, const int* __restrict__ obj,
    float* __restrict__ logits, int E, int D, int Nn, float scale) {
    int e = blockIdx.x * 4 + (threadIdx.x >> 6);
    int lane = threadIdx.x & 63;
    int s = sbj[e], o = obj[e];
    int d0 = lane * 16;
    const __bf16* r = rb + (size_t)e * D + d0;
    const float* Ps = P + (size_t)s * D + d0;
    const float* Qo = Q + (size_t)o * D + d0;
    const float* Pb = pb + d0;
    float a = 0.f;
#pragma unroll
    for (int u = 0; u < 16; ++u) a += (float)r[u] * (Ps[u] + Qo[u] + Pb[u]);
    a = wave_reduce_sum(a);
    if (lane == 0) {
        float tot = a + q[e] + nodeS[s] + nodeO[o] +
                    G_AD[(size_t)s * Nn + o] + G_BC[(size_t)o * Nn + s];
        logits[e] = tot * scale;
    }
}

__global__ __launch_bounds__(256) void segmax_kernel(const float* __restrict__ logits,
                                                     const int* __restrict__ sbj,
                                                     const int* __restrict__ obj,
                                                     unsigned* __restrict__ mS,
                                                     unsigned* __restrict__ mO, int E) {
    int e = blockIdx.x * 256 + threadIdx.x;
    if (e >= E) return;
    unsigned k = fenc(logits[e]);
    atomicMax(mS + sbj[e], k);
    atomicMax(mO + obj[e], k);
}

__global__ __launch_bounds__(256) void expsum_kernel(const float* __restrict__ logits,
                                                     const int* __restrict__ sbj,
                                                     const int* __restrict__ obj,
                                                     const unsigned* __restrict__ mS,
                                                     const unsigned* __restrict__ mO,
                                                     float* __restrict__ es, float* __restrict__ eo,
                                                     float* __restrict__ sumS, float* __restrict__ sumO,
                                                     int E) {
    int e = blockIdx.x * 256 + threadIdx.x;
    if (e >= E) return;
    float l = logits[e];
    int s = sbj[e], o = obj[e];
    float a = expf(l - fdec(mS[s]));
    es[e] = a;
    atomicAdd(sumS + s, a);
    float b = expf(l - fdec(mO[o]));
    eo[e] = b;
    atomicAdd(sumO + o, b);
}

__global__ __launch_bounds__(256) void scatter_kernel(const float* __restrict__ es,
                                                      const float* __restrict__ eo,
                                                      const float* __restrict__ sumS,
                                                      const float* __restrict__ sumO,
                                                      const int* __restrict__ sbj,
                                                      const int* __restrict__ obj,
                                                      float* __restrict__ S, int* __restrict__ inv,
                                                      int E, int Nn) {
    int e = blockIdx.x * 256 + threadIdx.x;
    if (e >= E) return;
    int s = sbj[e], o = obj[e];
    atomicAdd(S + (size_t)s * Nn + o, es[e] / sumS[s]);
    atomicAdd(S + (size_t)o * Nn + s, eo[e] / sumO[o]);
    inv[s] = 1;
    inv[o] = 1;
}

// ---------------- host launcher ----------------

extern "C" void kernel_launch(void* const* d_in, const int* in_sizes, int n_in,
                              void* d_out, int out_size, void* d_ws, size_t ws_size,
                              hipStream_t stream) {
    const float* V     = (const float*)d_in[0];
    const float* relv  = (const float*)d_in[1];
    const float* W_rel = (const float*)d_in[2];
    const float* b_rel = (const float*)d_in[3];
    const float* W_sbj = (const float*)d_in[4];
    const float* b_sbj = (const float*)d_in[5];
    const float* W_obj = (const float*)d_in[6];
    const float* b_obj = (const float*)d_in[7];
    const float* W_ctx = (const float*)d_in[8];
    const float* b_ctx = (const float*)d_in[9];
    const int* sbj = (const int*)d_in[10];
    const int* obj = (const int*)d_in[11];

    const int D  = in_sizes[3];
    const int E  = in_sizes[10];
    const int Nn = in_sizes[12];
    const size_t DD = (size_t)D * D;

    const float* Ws_v = W_sbj;
    const float* Ws_r = W_sbj + DD;
    const float* Wo_v = W_obj;
    const float* Wo_r = W_obj + DD;

    char* ws = (char*)d_ws;
    size_t off = 0;
    auto alloc = [&](size_t bytes) -> void* {
        void* p = (void*)(ws + off);
        off += (bytes + 255) & ~(size_t)255;
        return p;
    };

    // persistent
    __bf16* relv_b = (__bf16*)alloc((size_t)E * D * 2);
    __bf16* Vb     = (__bf16*)alloc((size_t)Nn * D * 2);
    __bf16* VbT    = (__bf16*)alloc((size_t)D * Nn * 2);
    __bf16* ZT_b   = (__bf16*)alloc(DD * 2);
    __bf16* KoKs   = (__bf16*)alloc((size_t)D * 2 * D * 2);   // [D][2048] = [Ko | Ks]
    __bf16* ACBD   = (__bf16*)alloc((size_t)Nn * 4 * D * 2);  // [Nn][4D] = [A|C|B|D]
    // region R1: Wr_all (3DD bf16) ... later G_AD+G_BC (2*Nn*Nn f32)
    size_t r1 = off;
    __bf16* Wr_all = (__bf16*)(ws + r1);
    float*  G_AD   = (float*)(ws + r1);
    float*  G_BC   = G_AD + (size_t)Nn * Nn;
    {
        size_t a = 3 * DD * 2, b = 2 * (size_t)Nn * Nn * 4;
        off += ((a > b ? a : b) + 255) & ~(size_t)255;
    }
    // region R2: Ws_rT + Wo_rT ... later W_ctxT
    size_t r2 = off;
    __bf16* Ws_rT  = (__bf16*)(ws + r2);
    __bf16* Wo_rT  = Ws_rT + DD;
    __bf16* W_ctxT = (__bf16*)(ws + r2);
    off += 2 * DD * 2;
    // region R3: MT_all (4DD bf16) ... later Pm+Qm (2*Nn*D f32)
    size_t r3 = off;
    __bf16* MT_all = (__bf16*)(ws + r3);                      // [4D][D] = [Ms^T;Mc^T;Mb^T;Md^T]
    float*  Pm     = (float*)(ws + r3);
    float*  Qm     = Pm + (size_t)Nn * D;
    {
        size_t a = 4 * DD * 2, b = 2 * (size_t)Nn * D * 4;
        off += ((a > b ? a : b) + 255) & ~(size_t)255;
    }
    float* pb     = (float*)alloc((size_t)D * 4);
    float* nodeS  = (float*)alloc((size_t)Nn * 4);
    float* nodeO  = (float*)alloc((size_t)Nn * 4);
    float* logits = (float*)alloc((size_t)E * 4);
    float* es     = (float*)alloc((size_t)E * 4);
    float* eo     = (float*)alloc((size_t)E * 4);
    size_t zbeg = off;
    float* S      = (float*)alloc((size_t)Nn * Nn * 4);
    float* q      = (float*)alloc((size_t)E * 4);
    float* bs     = (float*)alloc((size_t)D * 4);
    float* bo     = (float*)alloc((size_t)D * 4);
    unsigned* mS  = (unsigned*)alloc((size_t)Nn * 4);
    unsigned* mO  = (unsigned*)alloc((size_t)Nn * 4);
    float* sumS   = (float*)alloc((size_t)Nn * 4);
    float* sumO   = (float*)alloc((size_t)Nn * 4);
    int* inv      = (int*)alloc((size_t)Nn * 4);
    size_t zend = off;
    __bf16* Sb    = (__bf16*)alloc((size_t)Nn * Nn * 2);
    __bf16* ctx_b = (__bf16*)alloc((size_t)Nn * D * 2);
    (void)ws_size; (void)n_in; (void)out_size;

    float* outVj = (float*)d_out + (size_t)E * D;

    // 1. passthrough output 0 + zero atomic buffers
    hipMemcpyAsync(d_out, relv, (size_t)E * D * 4, hipMemcpyDeviceToDevice, stream);
    hipMemsetAsync(ws + zbeg, 0, zend - zbeg, stream);

    // 2. conversions
    auto cvt = [&](const float* in, __bf16* out, size_t n) {
        int blocks = (int)((n / 4 + 255) / 256);
        cvt_f32_bf16<<<dim3(blocks), dim3(256), 0, stream>>>(in, out, (long long)n);
    };
    auto cvtT = [&](const float* in, __bf16* out, int R, int C) {
        cvt_t_bf16<<<dim3(C / 32, R / 32), dim3(256), 0, stream>>>(in, out, R, C);
    };
    cvt(relv, relv_b, (size_t)E * D);
    cvt(W_rel, Wr_all, 3 * DD);
    cvt(V, Vb, (size_t)Nn * D);
    cvtT(Ws_r, Ws_rT, D, D);
    cvtT(Wo_r, Wo_rT, D, D);
    cvtT(V, VbT, Nn, D);

    __bf16* Wr_s_b = Wr_all;
    __bf16* Wr_o_b = Wr_all + DD;
    __bf16* Wr_r_b = Wr_all + 2 * DD;

    // 3. bias projections
    beta_kernel<<<dim3((D + 255) / 256, 32, 2), dim3(256), 0, stream>>>(
        b_rel, b_sbj, b_obj, Ws_r, Wo_r, bs, bo, D, (D + 31) / 32);

    // 4. GEMM launchers
    auto G64 = [&](auto modeTag, const __bf16* A, int ldA, const __bf16* Bt, int ldB,
                   int M, int N2, int K, const float* addMat, int ldAdd,
                   float* outF, __bf16* outB, int ldOut,
                   const __bf16* rbD, float* qO, const float* addRow, const int* mask) {
        gemm_gl<decltype(modeTag)::value, false><<<dim3(M / 64, N2 / 64), dim3(256), 0, stream>>>(
            A, ldA, Bt, ldB, M, N2, K, addMat, ldAdd, outF, outB, ldOut, rbD, qO, addRow, mask);
    };
    auto G128 = [&](auto modeTag, const __bf16* A, int ldA, const __bf16* Bt, int ldB,
                    int M, int N2, int K, const float* addMat, int ldAdd,
                    float* outF, __bf16* outB, int ldOut,
                    const __bf16* rbD, float* qO, const float* addRow, const int* mask) {
        gemm_gl<decltype(modeTag)::value, true><<<dim3(M / 128, N2 / 128), dim3(256), 0, stream>>>(
            A, ldA, Bt, ldB, M, N2, K, addMat, ldAdd, outF, outB, ldOut, rbD, qO, addRow, mask);
    };
    using M0 = std::integral_constant<int, 0>;
    using M1 = std::integral_constant<int, 1>;
    using M2 = std::integral_constant<int, 2>;
    using M3 = std::integral_constant<int, 3>;
    using M4 = std::integral_constant<int, 4>;

    // 5. W-side precomputes -> MT_all blocks (transposed writes)
    //    block0 Ms^T (= (Ws_v + Wr_s@Ws_r)^T), block1 Mc^T, block2 Mb^T, block3 Md^T
    G64(M1{}, Wr_s_b, D, Ws_rT, D, D, D, D, Ws_v, D, nullptr, MT_all + 0 * DD, D, nullptr, nullptr, nullptr, nullptr);
    G64(M1{}, Wr_s_b, D, Wo_rT, D, D, D, D, nullptr, 0, nullptr, MT_all + 1 * DD, D, nullptr, nullptr, nullptr, nullptr);
    G64(M1{}, Wr_o_b, D, Ws_rT, D, D, D, D, nullptr, 0, nullptr, MT_all + 2 * DD, D, nullptr, nullptr, nullptr, nullptr);
    G64(M1{}, Wr_o_b, D, Wo_rT, D, D, D, D, Wo_v, D, nullptr, MT_all + 3 * DD, D, nullptr, nullptr, nullptr, nullptr);
    // Ko = Wr_r@Wo_r -> KoKs[:, 0:D];  Ks = Wr_r@Ws_r -> KoKs[:, D:2D]
    G64(M0{}, Wr_r_b, D, Wo_rT, D, D, D, D, nullptr, 0, nullptr, KoKs + 0, 2 * D, nullptr, nullptr, nullptr, nullptr);
    G64(M0{}, Wr_r_b, D, Ws_rT, D, D, D, D, nullptr, 0, nullptr, KoKs + D, 2 * D, nullptr, nullptr, nullptr, nullptr);
    // W_ctxT now safe to overwrite R2
    cvtT(W_ctx, W_ctxT, D, D);
    // ZT = Ko @ Ks^T
    G64(M0{}, KoKs + 0, 2 * D, KoKs + D, 2 * D, D, D, D, nullptr, 0, nullptr, ZT_b, D, nullptr, nullptr, nullptr, nullptr);
    pbeta_kernel<<<dim3(D / 4), dim3(256), 0, stream>>>(bs, bo, KoKs, pb, D);

    // 6. fused N-side projections: ACBD = Vb @ MT_all^T  (768 x 4096)
    G128(M0{}, Vb, D, MT_all, D, Nn, 4 * D, D, nullptr, 0, nullptr, ACBD, 4 * D, nullptr, nullptr, nullptr, nullptr);

    // 7. Gram matrices (overwrite R1) + linear tables (overwrite R3)
    G64(M2{}, ACBD + 0 * D, 4 * D, ACBD + 3 * D, 4 * D, Nn, Nn, D, nullptr, 0, G_AD, nullptr, Nn, nullptr, nullptr, nullptr, nullptr);
    G64(M2{}, ACBD + 2 * D, 4 * D, ACBD + 1 * D, 4 * D, Nn, Nn, D, nullptr, 0, G_BC, nullptr, Nn, nullptr, nullptr, nullptr, nullptr);
    // P = A@Ko^T + C@Ks^T ; Q = B@Ko^T + D@Ks^T  (K = 2048, Bt = KoKs)
    G64(M2{}, ACBD + 0 * D, 4 * D, KoKs, 2 * D, Nn, D, 2 * D, nullptr, 0, Pm, nullptr, D, nullptr, nullptr, nullptr, nullptr);
    G64(M2{}, ACBD + 2 * D, 4 * D, KoKs, 2 * D, Nn, D, 2 * D, nullptr, 0, Qm, nullptr, D, nullptr, nullptr, nullptr, nullptr);

    node_kernel<<<dim3(Nn / 4), dim3(256), 0, stream>>>(ACBD, bs, bo, nodeS, nodeO, D);

    // 8. heavy: q[e] = (relv @ Z) . relv   (fused epilogue)
    G128(M3{}, relv_b, D, ZT_b, D, E, D, D, nullptr, 0, nullptr, nullptr, 0, relv_b, q, nullptr, nullptr);

    // 9. logits + segment softmaxes + scatter
    edge_logits_kernel<<<dim3(E / 4), dim3(256), 0, stream>>>(
        relv_b, Pm, Qm, pb, q, nodeS, nodeO, G_AD, G_BC, sbj, obj, logits, E, D, Nn,
        1.0f / sqrtf((float)D));
    segmax_kernel<<<dim3(E / 256), dim3(256), 0, stream>>>(logits, sbj, obj, mS, mO, E);
    expsum_kernel<<<dim3(E / 256), dim3(256), 0, stream>>>(logits, sbj, obj, mS, mO, es, eo, sumS, sumO, E);
    scatter_kernel<<<dim3(E / 256), dim3(256), 0, stream>>>(es, eo, sumS, sumO, sbj, obj, S, inv, E, Nn);

    // 10. ctx = S @ V ; vj update
    cvt(S, Sb, (size_t)Nn * Nn);
    G64(M0{}, Sb, Nn, VbT, Nn, Nn, D, Nn, nullptr, 0, nullptr, ctx_b, D, nullptr, nullptr, nullptr, nullptr);
    G64(M4{}, ctx_b, D, W_ctxT, D, Nn, D, D, V, D, outVj, nullptr, D, nullptr, nullptr, b_ctx, inv);
}

// Round 4
// 398.437 us; speedup vs baseline: 2.4824x; 1.3384x over previous
//
#include <hip/hip_runtime.h>
#include <hip/hip_bf16.h>
#include <math.h>
#include <type_traits>

typedef __bf16 v8bf __attribute__((ext_vector_type(8)));
typedef __bf16 v4bf __attribute__((ext_vector_type(4)));
typedef float  v4f  __attribute__((ext_vector_type(4)));

__device__ __forceinline__ float wave_reduce_sum(float v) {
#pragma unroll
    for (int m = 1; m < 64; m <<= 1) v += __shfl_xor(v, m, 64);
    return v;
}

__device__ __forceinline__ unsigned fenc(float x) {
    unsigned u = __float_as_uint(x);
    return (u & 0x80000000u) ? ~u : (u | 0x80000000u);
}
__device__ __forceinline__ float fdec(unsigned k) {
    return (k & 0x80000000u) ? __uint_as_float(k ^ 0x80000000u) : __uint_as_float(~k);
}

__device__ __forceinline__ void gload16(const void* g, void* l) {
    __builtin_amdgcn_global_load_lds((const __attribute__((address_space(1))) void*)g,
                                     (__attribute__((address_space(3))) void*)l, 16, 0, 0);
}

// ---------------- conversion kernels ----------------

__global__ __launch_bounds__(256) void cvt_f32_bf16(const float* __restrict__ in,
                                                    __bf16* __restrict__ out, long long n) {
    long long i = ((long long)blockIdx.x * 256 + threadIdx.x) * 4;
    if (i >= n) return;
    v4f v = *(const v4f*)(in + i);
    v4bf o;
    o[0] = (__bf16)v[0]; o[1] = (__bf16)v[1]; o[2] = (__bf16)v[2]; o[3] = (__bf16)v[3];
    *(v4bf*)(out + i) = o;
}

// fused: outCopy = in (f32), outB = bf16(in). Reads the 100 MB relv once.
__global__ __launch_bounds__(256) void copy_cvt(const float* __restrict__ in,
                                                float* __restrict__ outCopy,
                                                __bf16* __restrict__ outB, long long n) {
    long long i = ((long long)blockIdx.x * 256 + threadIdx.x) * 4;
    if (i >= n) return;
    v4f v = *(const v4f*)(in + i);
    *(v4f*)(outCopy + i) = v;
    v4bf o;
    o[0] = (__bf16)v[0]; o[1] = (__bf16)v[1]; o[2] = (__bf16)v[2]; o[3] = (__bf16)v[3];
    *(v4bf*)(outB + i) = o;
}

// out[c][r] = (bf16) in[r][c];  R,C multiples of 32
__global__ __launch_bounds__(256) void cvt_t_bf16(const float* __restrict__ in,
                                                  __bf16* __restrict__ out, int R, int C) {
    __shared__ float tile[32][33];
    int cb = blockIdx.x * 32, rb = blockIdx.y * 32;
    int tx = threadIdx.x & 31, ty = threadIdx.x >> 5;
#pragma unroll
    for (int i = 0; i < 32; i += 8)
        tile[ty + i][tx] = in[(size_t)(rb + ty + i) * C + cb + tx];
    __syncthreads();
#pragma unroll
    for (int i = 0; i < 32; i += 8)
        out[(size_t)(cb + ty + i) * R + rb + tx] = (__bf16)tile[tx][ty + i];
}

// ---- bf16 MFMA GEMM, m97 structure + XOR-swizzled LDS (rule #21) ----
// out = A (MxK, ldA) @ Bt^T (Bt is NxK, ldB).  grid.z batching via zA/zB/zOut.
// MODE 0: outB (bf16, plain, ldOut) = acc (+addMat f32 [ldAdd] if non-null)
// MODE 2: outF (f32, plain, ldOut)  = acc
// MODE 3: fused row-dot: atomicAdd(qOut[m], sum_n acc[m][n]*rbDot[m][n])
// MODE 4: outF[m][n] = addMat[m][n] + (maskRow[m] ? acc + addRow[n] : 0)
// MODE 5: W-combo epilogue (M=3D, N=2D): m-blocks {Wr_s,Wr_o,Wr_r} x n-blocks {Wo_r,Ws_r}
//         (0,0)->Mc^T blk1, (0,1)->Ms^T blk0 (+addMat=Ws_v), (1,0)->Md^T blk3 (+addRow=Wo_v),
//         (1,1)->Mb^T blk2  into outB [4D][D];  (2,*) -> outB2 = KoKs [D][2D] plain.
template <int MODE, bool BIG>
__global__ __launch_bounds__(256) void gemm_gl(
    const __bf16* __restrict__ Ap, int ldA,
    const __bf16* __restrict__ Btp, int ldB,
    int M, int N, int K,
    long zA, long zB, long zOut,
    const float* __restrict__ addMat, int ldAdd,
    float* __restrict__ outF,
    __bf16* __restrict__ outB, int ldOut,
    __bf16* __restrict__ outB2,
    const __bf16* __restrict__ rbDot,
    float* __restrict__ qOut,
    const float* __restrict__ addRow,
    const int* __restrict__ maskRow) {
    constexpr int BM = BIG ? 128 : 64;
    constexpr int BN = BIG ? 128 : 64;
    constexpr int WM = BM / 2, WN = BN / 2;
    constexpr int FI = WM / 16, FJ = WN / 16;
    constexpr int NLA = (BM * 64) / 2048;
    constexpr int NLB = (BN * 64) / 2048;

    __shared__ alignas(16) __bf16 As[BM * 64];
    __shared__ alignas(16) __bf16 Bs[BN * 64];

    Ap  += zA * (long)blockIdx.z;
    Btp += zB * (long)blockIdx.z;
    outF += zOut * (long)blockIdx.z;

    const int m0 = blockIdx.x * BM, n0 = blockIdx.y * BN;
    const int t = threadIdx.x, lane = t & 63, wid = t >> 6;
    const int wm = wid >> 1, wn = wid & 1;
    const int rA = t >> 3;
    const int cSw = (t & 7) ^ (rA & 7);            // swizzled 16B-chunk (involution)

    v4f acc[FI][FJ] = {};

    const int l15 = lane & 15;
    const int xorMask = (l15 & 7) << 4;            // read-side XOR (bytes)

    for (int kt = 0; kt < K; kt += 64) {
#pragma unroll
        for (int i = 0; i < NLA; ++i)
            gload16(Ap + (size_t)(m0 + i * 32 + rA) * ldA + kt + cSw * 8,
                    (char*)As + i * 4096 + wid * 1024);
#pragma unroll
        for (int i = 0; i < NLB; ++i)
            gload16(Btp + (size_t)(n0 + i * 32 + rA) * ldB + kt + cSw * 8,
                    (char*)Bs + i * 4096 + wid * 1024);
        __syncthreads();
#pragma unroll
        for (int ks = 0; ks < 2; ++ks) {
            const int kb = (ks * 64 + ((lane >> 4) << 4)) ^ xorMask;
            v8bf af[FI], bfr[FJ];
#pragma unroll
            for (int f = 0; f < FI; ++f)
                af[f] = *(const v8bf*)((const char*)As + (wm * WM + f * 16 + l15) * 128 + kb);
#pragma unroll
            for (int f = 0; f < FJ; ++f)
                bfr[f] = *(const v8bf*)((const char*)Bs + (wn * WN + f * 16 + l15) * 128 + kb);
#pragma unroll
            for (int i = 0; i < FI; ++i)
#pragma unroll
                for (int j = 0; j < FJ; ++j)
                    acc[i][j] = __builtin_amdgcn_mfma_f32_16x16x32_bf16(af[i], bfr[j], acc[i][j], 0, 0, 0);
        }
        __syncthreads();
    }

    const int cc = lane & 15, r4 = (lane >> 4) << 2;
    if constexpr (MODE == 3) {
#pragma unroll
        for (int i = 0; i < FI; ++i)
#pragma unroll
            for (int r = 0; r < 4; ++r) {
                const int gm = m0 + wm * WM + i * 16 + r4 + r;
                float p = 0.f;
#pragma unroll
                for (int j = 0; j < FJ; ++j) {
                    const int gn = n0 + wn * WN + j * 16 + cc;
                    p += acc[i][j][r] * (float)rbDot[(size_t)gm * N + gn];
                }
                p += __shfl_xor(p, 1, 64);
                p += __shfl_xor(p, 2, 64);
                p += __shfl_xor(p, 4, 64);
                p += __shfl_xor(p, 8, 64);
                if (cc == 0) atomicAdd(qOut + gm, p);
            }
    } else if constexpr (MODE == 5) {
        const int mb = m0 >> 10, nb = n0 >> 10;
        const size_t DDe = (size_t)ldOut * ldOut;
#pragma unroll
        for (int i = 0; i < FI; ++i)
#pragma unroll
            for (int j = 0; j < FJ; ++j)
#pragma unroll
                for (int r = 0; r < 4; ++r) {
                    const int gm = m0 + wm * WM + i * 16 + r4 + r;
                    const int gn = n0 + wn * WN + j * 16 + cc;
                    const int gml = gm & 1023, gnl = gn & 1023;
                    float v = acc[i][j][r];
                    if (mb == 2) {
                        outB2[(size_t)gml * 2048 + gn] = (__bf16)v;
                    } else {
                        int blk;
                        if (mb == 0) { blk = nb ? 0 : 1; if (nb) v += addMat[(size_t)gml * ldAdd + gnl]; }
                        else         { blk = nb ? 2 : 3; if (!nb) v += addRow[(size_t)gml * ldAdd + gnl]; }
                        outB[blk * DDe + (size_t)gnl * ldOut + gml] = (__bf16)v;
                    }
                }
    } else {
#pragma unroll
        for (int i = 0; i < FI; ++i)
#pragma unroll
            for (int j = 0; j < FJ; ++j)
#pragma unroll
                for (int r = 0; r < 4; ++r) {
                    const int gm = m0 + wm * WM + i * 16 + r4 + r;
                    const int gn = n0 + wn * WN + j * 16 + cc;
                    float v = acc[i][j][r];
                    if constexpr (MODE == 0) {
                        if (addMat) v += addMat[(size_t)gm * ldAdd + gn];
                        outB[(size_t)gm * ldOut + gn] = (__bf16)v;
                    } else if constexpr (MODE == 2) {
                        outF[(size_t)gm * ldOut + gn] = v;
                    } else {  // MODE 4
                        float u = addMat[(size_t)gm * ldAdd + gn];
                        if (maskRow[gm]) u += v + addRow[gn];
                        outF[(size_t)gm * ldOut + gn] = u;
                    }
                }
    }
}

// ---------------- small custom kernels ----------------

__global__ __launch_bounds__(256) void beta_kernel(
    const float* __restrict__ b_rel, const float* __restrict__ b_sbj, const float* __restrict__ b_obj,
    const float* __restrict__ Wsr, const float* __restrict__ Wor,
    float* __restrict__ bs, float* __restrict__ bo, int D, int rowsPerChunk) {
    const int col = blockIdx.x * 256 + threadIdx.x;
    if (col >= D) return;
    const int r0 = blockIdx.y * rowsPerChunk;
    const float* W = (blockIdx.z == 0) ? Wsr : Wor;
    float acc = 0.f;
    if (blockIdx.y == 0) acc = (blockIdx.z == 0) ? b_sbj[col] : b_obj[col];
    const int rEnd = min(r0 + rowsPerChunk, D);
    for (int r = r0; r < rEnd; ++r)
        acc += b_rel[r] * W[(size_t)r * D + col];
    float* out = (blockIdx.z == 0) ? bs : bo;
    atomicAdd(out + col, acc);
}

// pb[d] = sum_j bs[j]*Ko[d][j] + bo[j]*Ks[d][j];  KoKs = [D][2048] = [Ko | Ks]
__global__ __launch_bounds__(256) void pbeta_kernel(const float* __restrict__ bs,
                                                    const float* __restrict__ bo,
                                                    const __bf16* __restrict__ KoKs,
                                                    float* __restrict__ pb, int D) {
    int d = blockIdx.x * 4 + (threadIdx.x >> 6);
    int lane = threadIdx.x & 63;
    float a = 0.f;
    for (int j = lane; j < D; j += 64)
        a += bs[j] * (float)KoKs[(size_t)d * 2048 + j] + bo[j] * (float)KoKs[(size_t)d * 2048 + 1024 + j];
    a = wave_reduce_sum(a);
    if (lane == 0) pb[d] = a;
}

// ACBD = [A | C | B | D] row blocks of width D, ld = 4D
__global__ __launch_bounds__(256) void node_kernel(
    const __bf16* __restrict__ ACBD,
    const float* __restrict__ bs, const float* __restrict__ bo,
    float* __restrict__ nodeS, float* __restrict__ nodeO, int D) {
    int n = blockIdx.x * 4 + (threadIdx.x >> 6);
    int lane = threadIdx.x & 63;
    int d0 = lane * 16;
    const __bf16* row = ACBD + (size_t)n * 4 * D;
    const __bf16* pa = row + d0;
    const __bf16* pc = row + D + d0;
    const __bf16* pB = row + 2 * D + d0;
    const __bf16* pd = row + 3 * D + d0;
    float s1 = 0.f, s2 = 0.f;
#pragma unroll
    for (int u = 0; u < 16; ++u) {
        float a = (float)pa[u], c = (float)pc[u], b = (float)pB[u], dd = (float)pd[u];
        float vs_ = bs[d0 + u], vo_ = bo[d0 + u];
        s1 += a * c + a * vo_ + vs_ * c;
        s2 += b * dd + b * vo_ + vs_ * dd;
    }
    s1 = wave_reduce_sum(s1);
    s2 = wave_reduce_sum(s2);
    if (lane == 0) { nodeS[n] = s1; nodeO[n] = s2; }
}

__global__ __launch_bounds__(256) void edge_logits_kernel(
    const __bf16* __restrict__ rb, const float* __restrict__ P, const float* __restrict__ Q,
    const float* __restrict__ pb, const float* __restrict__ q,
    const float* __restrict__ nodeS, const float* __restrict__ nodeO,
    const float* __restrict__ G_AD, const float* __restrict__ G_BC,
    const int* __restrict__ sbj, const int* __restrict__ obj,
    float* __restrict__ logits, int E, int D, int Nn, float scale) {
    int e = blockIdx.x * 4 + (threadIdx.x >> 6);
    int lane = threadIdx.x & 63;
    int s = sbj[e], o = obj[e];
    int d0 = lane * 16;
    const __bf16* r = rb + (size_t)e * D + d0;
    const float* Ps = P + (size_t)s * D + d0;
    const float* Qo = Q + (size_t)o * D + d0;
    const float* Pb = pb + d0;
    float a = 0.f;
#pragma unroll
    for (int u = 0; u < 16; ++u) a += (float)r[u] * (Ps[u] + Qo[u] + Pb[u]);
    a = wave_reduce_sum(a);
    if (lane == 0) {
        float tot = a + q[e] + nodeS[s] + nodeO[o] +
                    G_AD[(size_t)s * Nn + o] + G_BC[(size_t)o * Nn + s];
        logits[e] = tot * scale;
    }
}

__global__ __launch_bounds__(256) void segmax_kernel(const float* __restrict__ logits,
                                                     const int* __restrict__ sbj,
                                                     const int* __restrict__ obj,
                                                     unsigned* __restrict__ mS,
                                                     unsigned* __restrict__ mO, int E) {
    int e = blockIdx.x * 256 + threadIdx.x;
    if (e >= E) return;
    unsigned k = fenc(logits[e]);
    atomicMax(mS + sbj[e], k);
    atomicMax(mO + obj[e], k);
}

__global__ __launch_bounds__(256) void expsum_kernel(const float* __restrict__ logits,
                                                     const int* __restrict__ sbj,
                                                     const int* __restrict__ obj,
                                                     const unsigned* __restrict__ mS,
                                                     const unsigned* __restrict__ mO,
                                                     float* __restrict__ es, float* __restrict__ eo,
                                                     float* __restrict__ sumS, float* __restrict__ sumO,
                                                     int E) {
    int e = blockIdx.x * 256 + threadIdx.x;
    if (e >= E) return;
    float l = logits[e];
    int s = sbj[e], o = obj[e];
    float a = expf(l - fdec(mS[s]));
    es[e] = a;
    atomicAdd(sumS + s, a);
    float b = expf(l - fdec(mO[o]));
    eo[e] = b;
    atomicAdd(sumO + o, b);
}

__global__ __launch_bounds__(256) void scatter_kernel(const float* __restrict__ es,
                                                      const float* __restrict__ eo,
                                                      const float* __restrict__ sumS,
                                                      const float* __restrict__ sumO,
                                                      const int* __restrict__ sbj,
                                                      const int* __restrict__ obj,
                                                      float* __restrict__ S, int* __restrict__ inv,
                                                      int E, int Nn) {
    int e = blockIdx.x * 256 + threadIdx.x;
    if (e >= E) return;
    int s = sbj[e], o = obj[e];
    atomicAdd(S + (size_t)s * Nn + o, es[e] / sumS[s]);
    atomicAdd(S + (size_t)o * Nn + s, eo[e] / sumO[o]);
    inv[s] = 1;
    inv[o] = 1;
}

// ---------------- host launcher ----------------

extern "C" void kernel_launch(void* const* d_in, const int* in_sizes, int n_in,
                              void* d_out, int out_size, void* d_ws, size_t ws_size,
                              hipStream_t stream) {
    const float* V     = (const float*)d_in[0];
    const float* relv  = (const float*)d_in[1];
    const float* W_rel = (const float*)d_in[2];
    const float* b_rel = (const float*)d_in[3];
    const float* W_sbj = (const float*)d_in[4];
    const float* b_sbj = (const float*)d_in[5];
    const float* W_obj = (const float*)d_in[6];
    const float* b_obj = (const float*)d_in[7];
    const float* W_ctx = (const float*)d_in[8];
    const float* b_ctx = (const float*)d_in[9];
    const int* sbj = (const int*)d_in[10];
    const int* obj = (const int*)d_in[11];

    const int D  = in_sizes[3];
    const int E  = in_sizes[10];
    const int Nn = in_sizes[12];
    const size_t DD = (size_t)D * D;

    const float* Ws_v = W_sbj;
    const float* Ws_r = W_sbj + DD;
    const float* Wo_v = W_obj;
    const float* Wo_r = W_obj + DD;

    char* ws = (char*)d_ws;
    size_t off = 0;
    auto alloc = [&](size_t bytes) -> void* {
        void* p = (void*)(ws + off);
        off += (bytes + 255) & ~(size_t)255;
        return p;
    };

    // persistent
    __bf16* relv_b = (__bf16*)alloc((size_t)E * D * 2);
    __bf16* Vb     = (__bf16*)alloc((size_t)Nn * D * 2);
    __bf16* VbT    = (__bf16*)alloc((size_t)D * Nn * 2);
    __bf16* ZT_b   = (__bf16*)alloc(DD * 2);
    __bf16* KoKs   = (__bf16*)alloc((size_t)D * 2 * D * 2);   // [D][2048] = [Ko | Ks]
    __bf16* ACBD   = (__bf16*)alloc((size_t)Nn * 4 * D * 2);  // [Nn][4D] = [A|C|B|D]
    // region R1: Wr_all (3DD bf16) ... later G_AD+G_BC (2*Nn*Nn f32)
    size_t r1 = off;
    __bf16* Wr_all = (__bf16*)(ws + r1);
    float*  G_AD   = (float*)(ws + r1);
    float*  G_BC   = G_AD + (size_t)Nn * Nn;
    {
        size_t a = 3 * DD * 2, b = 2 * (size_t)Nn * Nn * 4;
        off += ((a > b ? a : b) + 255) & ~(size_t)255;
    }
    // region R2: WoWs_T (2DD bf16: [Wo_rT ; Ws_rT]) ... later W_ctxT
    size_t r2 = off;
    __bf16* WoWs_T = (__bf16*)(ws + r2);
    __bf16* W_ctxT = (__bf16*)(ws + r2);
    off += 2 * DD * 2;
    // region R3: MT_all (4DD bf16: [Ms^T;Mc^T;Mb^T;Md^T]) ... later Pm+Qm
    size_t r3 = off;
    __bf16* MT_all = (__bf16*)(ws + r3);
    float*  Pm     = (float*)(ws + r3);
    float*  Qm     = Pm + (size_t)Nn * D;
    {
        size_t a = 4 * DD * 2, b = 2 * (size_t)Nn * D * 4;
        off += ((a > b ? a : b) + 255) & ~(size_t)255;
    }
    float* pb     = (float*)alloc((size_t)D * 4);
    float* nodeS  = (float*)alloc((size_t)Nn * 4);
    float* nodeO  = (float*)alloc((size_t)Nn * 4);
    float* logits = (float*)alloc((size_t)E * 4);
    float* es     = (float*)alloc((size_t)E * 4);
    float* eo     = (float*)alloc((size_t)E * 4);
    size_t zbeg = off;
    float* S      = (float*)alloc((size_t)Nn * Nn * 4);
    float* q      = (float*)alloc((size_t)E * 4);
    float* bs     = (float*)alloc((size_t)D * 4);
    float* bo     = (float*)alloc((size_t)D * 4);
    unsigned* mS  = (unsigned*)alloc((size_t)Nn * 4);
    unsigned* mO  = (unsigned*)alloc((size_t)Nn * 4);
    float* sumS   = (float*)alloc((size_t)Nn * 4);
    float* sumO   = (float*)alloc((size_t)Nn * 4);
    int* inv      = (int*)alloc((size_t)Nn * 4);
    size_t zend = off;
    __bf16* Sb    = (__bf16*)alloc((size_t)Nn * Nn * 2);
    __bf16* ctx_b = (__bf16*)alloc((size_t)Nn * D * 2);
    (void)ws_size; (void)n_in; (void)out_size;

    float* outVj = (float*)d_out + (size_t)E * D;

    // 1. zero atomic buffers
    hipMemsetAsync(ws + zbeg, 0, zend - zbeg, stream);

    // 2. conversions (passthrough fused with relv cvt)
    auto cvt = [&](const float* in, __bf16* out, size_t n) {
        int blocks = (int)((n / 4 + 255) / 256);
        cvt_f32_bf16<<<dim3(blocks), dim3(256), 0, stream>>>(in, out, (long long)n);
    };
    auto cvtT = [&](const float* in, __bf16* out, int R, int C) {
        cvt_t_bf16<<<dim3(C / 32, R / 32), dim3(256), 0, stream>>>(in, out, R, C);
    };
    {
        long long n = (long long)E * D;
        copy_cvt<<<dim3((int)(n / 4 / 256)), dim3(256), 0, stream>>>(relv, (float*)d_out, relv_b, n);
    }
    cvt(W_rel, Wr_all, 3 * DD);
    cvt(V, Vb, (size_t)Nn * D);
    cvtT(Wo_r, WoWs_T, D, D);          // rows 0..D-1  = Wo_rT
    cvtT(Ws_r, WoWs_T + DD, D, D);     // rows D..2D-1 = Ws_rT
    cvtT(V, VbT, Nn, D);

    // 3. bias projections
    beta_kernel<<<dim3((D + 255) / 256, 32, 2), dim3(256), 0, stream>>>(
        b_rel, b_sbj, b_obj, Ws_r, Wo_r, bs, bo, D, (D + 31) / 32);

    // 4. GEMM launcher
    auto G = [&](auto modeTag, auto bigTag, const __bf16* A, int ldA, const __bf16* Bt, int ldB,
                 int M, int N2, int K, int nz, long zA, long zB, long zOut,
                 const float* addMat, int ldAdd, float* outF, __bf16* outB, int ldOut,
                 __bf16* outB2, const __bf16* rbD, float* qO, const float* addRow, const int* mask) {
        constexpr int BT = decltype(bigTag)::value ? 128 : 64;
        gemm_gl<decltype(modeTag)::value, decltype(bigTag)::value>
            <<<dim3(M / BT, N2 / BT, nz), dim3(256), 0, stream>>>(
                A, ldA, Bt, ldB, M, N2, K, zA, zB, zOut, addMat, ldAdd, outF, outB, ldOut,
                outB2, rbD, qO, addRow, mask);
    };
    using M0 = std::integral_constant<int, 0>;
    using M2 = std::integral_constant<int, 2>;
    using M3 = std::integral_constant<int, 3>;
    using M4 = std::integral_constant<int, 4>;
    using M5 = std::integral_constant<int, 5>;
    using SMALL = std::integral_constant<bool, false>;
    using LARGE = std::integral_constant<bool, true>;

    // 5. merged W-side precompute: [Wr_s;Wr_o;Wr_r] @ [Wo_r | Ws_r]  (3072 x 2048 x 1024)
    //    -> MT_all blocks (transposed, +Ws_v/+Wo_v) and KoKs = [Ko|Ks]
    G(M5{}, LARGE{}, Wr_all, D, WoWs_T, D, 3 * D, 2 * D, D, 1, 0, 0, 0,
      Ws_v, D, nullptr, MT_all, D, KoKs, nullptr, nullptr, Wo_v, nullptr);
    // W_ctxT now safe to overwrite R2
    cvtT(W_ctx, W_ctxT, D, D);
    // ZT = Ko @ Ks^T
    G(M0{}, SMALL{}, KoKs + 0, 2 * D, KoKs + D, 2 * D, D, D, D, 1, 0, 0, 0,
      nullptr, 0, nullptr, ZT_b, D, nullptr, nullptr, nullptr, nullptr, nullptr);
    pbeta_kernel<<<dim3(D / 4), dim3(256), 0, stream>>>(bs, bo, KoKs, pb, D);

    // 6. fused N-side projections: ACBD = Vb @ MT_all^T  (768 x 4096)
    G(M0{}, SMALL{}, Vb, D, MT_all, D, Nn, 4 * D, D, 1, 0, 0, 0,
      nullptr, 0, nullptr, ACBD, 4 * D, nullptr, nullptr, nullptr, nullptr, nullptr);

    // 7. batched Grams (z=0: A@D^T -> G_AD, z=1: B@C^T -> G_BC), overwrite R1
    G(M2{}, SMALL{}, ACBD + 0 * D, 4 * D, ACBD + 3 * D, 4 * D, Nn, Nn, D, 2,
      2 * (long)D, -2 * (long)D, (long)Nn * Nn,
      nullptr, 0, G_AD, nullptr, Nn, nullptr, nullptr, nullptr, nullptr, nullptr);
    // batched P/Q (K=2048): z=0: [A|C]@[Ko|Ks]^T -> Pm, z=1: [B|D]@... -> Qm (overwrite R3)
    G(M2{}, SMALL{}, ACBD + 0 * D, 4 * D, KoKs, 2 * D, Nn, D, 2 * D, 2,
      2 * (long)D, 0, (long)Nn * D,
      nullptr, 0, Pm, nullptr, D, nullptr, nullptr, nullptr, nullptr, nullptr);

    node_kernel<<<dim3(Nn / 4), dim3(256), 0, stream>>>(ACBD, bs, bo, nodeS, nodeO, D);

    // 8. heavy: q[e] = (relv @ Z) . relv   (fused epilogue)
    G(M3{}, LARGE{}, relv_b, D, ZT_b, D, E, D, D, 1, 0, 0, 0,
      nullptr, 0, nullptr, nullptr, 0, nullptr, relv_b, q, nullptr, nullptr);

    // 9. logits + segment softmaxes + scatter
    edge_logits_kernel<<<dim3(E / 4), dim3(256), 0, stream>>>(
        relv_b, Pm, Qm, pb, q, nodeS, nodeO, G_AD, G_BC, sbj, obj, logits, E, D, Nn,
        1.0f / sqrtf((float)D));
    segmax_kernel<<<dim3(E / 256), dim3(256), 0, stream>>>(logits, sbj, obj, mS, mO, E);
    expsum_kernel<<<dim3(E / 256), dim3(256), 0, stream>>>(logits, sbj, obj, mS, mO, es, eo, sumS, sumO, E);
    scatter_kernel<<<dim3(E / 256), dim3(256), 0, stream>>>(es, eo, sumS, sumO, sbj, obj, S, inv, E, Nn);

    // 10. ctx = S @ V ; vj update
    cvt(S, Sb, (size_t)Nn * Nn);
    G(M0{}, SMALL{}, Sb, Nn, VbT, Nn, Nn, D, Nn, 1, 0, 0, 0,
      nullptr, 0, nullptr, ctx_b, D, nullptr, nullptr, nullptr, nullptr, nullptr);
    G(M4{}, SMALL{}, ctx_b, D, W_ctxT, D, Nn, D, D, 1, 0, 0, 0,
      V, D, outVj, nullptr, D, nullptr, nullptr, nullptr, b_ctx, inv);
}

// Round 5
// 380.379 us; speedup vs baseline: 2.6002x; 1.0475x over previous
//
#include <hip/hip_runtime.h>
#include <hip/hip_bf16.h>
#include <math.h>
#include <type_traits>

typedef __bf16 v8bf __attribute__((ext_vector_type(8)));
typedef __bf16 v4bf __attribute__((ext_vector_type(4)));
typedef float  v4f  __attribute__((ext_vector_type(4)));

__device__ __forceinline__ float wave_reduce_sum(float v) {
#pragma unroll
    for (int m = 1; m < 64; m <<= 1) v += __shfl_xor(v, m, 64);
    return v;
}

__device__ __forceinline__ unsigned fenc(float x) {
    unsigned u = __float_as_uint(x);
    return (u & 0x80000000u) ? ~u : (u | 0x80000000u);
}
__device__ __forceinline__ float fdec(unsigned k) {
    return (k & 0x80000000u) ? __uint_as_float(k ^ 0x80000000u) : __uint_as_float(~k);
}

__device__ __forceinline__ void gload16(const void* g, void* l) {
    __builtin_amdgcn_global_load_lds((const __attribute__((address_space(1))) void*)g,
                                     (__attribute__((address_space(3))) void*)l, 16, 0, 0);
}

// ---------------- conversion kernels ----------------

__global__ __launch_bounds__(256) void cvt_f32_bf16(const float* __restrict__ in,
                                                    __bf16* __restrict__ out, long long n) {
    long long i = ((long long)blockIdx.x * 256 + threadIdx.x) * 4;
    if (i >= n) return;
    v4f v = *(const v4f*)(in + i);
    v4bf o;
    o[0] = (__bf16)v[0]; o[1] = (__bf16)v[1]; o[2] = (__bf16)v[2]; o[3] = (__bf16)v[3];
    *(v4bf*)(out + i) = o;
}

// fused: outCopy = in (f32), outB = bf16(in). Reads the 100 MB relv once.
__global__ __launch_bounds__(256) void copy_cvt(const float* __restrict__ in,
                                                float* __restrict__ outCopy,
                                                __bf16* __restrict__ outB, long long n) {
    long long i = ((long long)blockIdx.x * 256 + threadIdx.x) * 4;
    if (i >= n) return;
    v4f v = *(const v4f*)(in + i);
    *(v4f*)(outCopy + i) = v;
    v4bf o;
    o[0] = (__bf16)v[0]; o[1] = (__bf16)v[1]; o[2] = (__bf16)v[2]; o[3] = (__bf16)v[3];
    *(v4bf*)(outB + i) = o;
}

// out[c][r] = (bf16) in[r][c];  R,C multiples of 32
__global__ __launch_bounds__(256) void cvt_t_bf16(const float* __restrict__ in,
                                                  __bf16* __restrict__ out, int R, int C) {
    __shared__ float tile[32][33];
    int cb = blockIdx.x * 32, rb = blockIdx.y * 32;
    int tx = threadIdx.x & 31, ty = threadIdx.x >> 5;
#pragma unroll
    for (int i = 0; i < 32; i += 8)
        tile[ty + i][tx] = in[(size_t)(rb + ty + i) * C + cb + tx];
    __syncthreads();
#pragma unroll
    for (int i = 0; i < 32; i += 8)
        out[(size_t)(cb + ty + i) * R + rb + tx] = (__bf16)tile[tx][ty + i];
}

// ---- bf16 MFMA GEMM, m97 structure + XOR-swizzled LDS (rule #21) ----
// out = A (MxK, ldA) @ Bt^T (Bt is NxK, ldB).  grid.z batching via zA/zB/zOut.
// MODE 0: outB (bf16, plain, ldOut) = acc (+addMat f32 [ldAdd] if non-null)
// MODE 2: outF (f32, plain, ldOut)  = acc
// MODE 3: fused logits partial: atomicAdd(qOut[m],
//           sum_n rbDot[m][n]*(acc[m][n] + addMat[s[m]][n] + outF[o[m]][n] + addRow[n]))
//         with addMat=Pm (ldAdd), outF=Qm, addRow=pb, sbjI/objI row indices.
// MODE 4: outF[m][n] = addMat[m][n] + (maskRow[m] ? acc + addRow[n] : 0)
// MODE 5: W-combo epilogue (M=3D, N=2D): m-blocks {Wr_s,Wr_o,Wr_r} x n-blocks {Wo_r,Ws_r}
//         (0,0)->Mc^T blk1, (0,1)->Ms^T blk0 (+addMat=Ws_v), (1,0)->Md^T blk3 (+addRow=Wo_v),
//         (1,1)->Mb^T blk2  into outB [4D][D];  (2,*) -> outB2 = KoKs [D][2D] plain.
template <int MODE, bool BIG>
__global__ __launch_bounds__(256, 4) void gemm_gl(
    const __bf16* __restrict__ Ap, int ldA,
    const __bf16* __restrict__ Btp, int ldB,
    int M, int N, int K,
    long zA, long zB, long zOut,
    const float* __restrict__ addMat, int ldAdd,
    float* __restrict__ outF,
    __bf16* __restrict__ outB, int ldOut,
    __bf16* __restrict__ outB2,
    const __bf16* __restrict__ rbDot,
    float* __restrict__ qOut,
    const float* __restrict__ addRow,
    const int* __restrict__ maskRow,
    const int* __restrict__ sbjI,
    const int* __restrict__ objI) {
    constexpr int BM = BIG ? 128 : 64;
    constexpr int BN = BIG ? 128 : 64;
    constexpr int WM = BM / 2, WN = BN / 2;
    constexpr int FI = WM / 16, FJ = WN / 16;
    constexpr int NLA = (BM * 64) / 2048;
    constexpr int NLB = (BN * 64) / 2048;

    __shared__ alignas(16) __bf16 As[BM * 64];
    __shared__ alignas(16) __bf16 Bs[BN * 64];

    Ap  += zA * (long)blockIdx.z;
    Btp += zB * (long)blockIdx.z;
    outF += zOut * (long)blockIdx.z;

    const int m0 = blockIdx.x * BM, n0 = blockIdx.y * BN;
    const int t = threadIdx.x, lane = t & 63, wid = t >> 6;
    const int wm = wid >> 1, wn = wid & 1;
    const int rA = t >> 3;
    const int cSw = (t & 7) ^ (rA & 7);            // swizzled 16B-chunk (involution)

    v4f acc[FI][FJ] = {};

    const int l15 = lane & 15;
    const int xorMask = (l15 & 7) << 4;            // read-side XOR (bytes)

    for (int kt = 0; kt < K; kt += 64) {
#pragma unroll
        for (int i = 0; i < NLA; ++i)
            gload16(Ap + (size_t)(m0 + i * 32 + rA) * ldA + kt + cSw * 8,
                    (char*)As + i * 4096 + wid * 1024);
#pragma unroll
        for (int i = 0; i < NLB; ++i)
            gload16(Btp + (size_t)(n0 + i * 32 + rA) * ldB + kt + cSw * 8,
                    (char*)Bs + i * 4096 + wid * 1024);
        __syncthreads();
#pragma unroll
        for (int ks = 0; ks < 2; ++ks) {
            const int kb = (ks * 64 + ((lane >> 4) << 4)) ^ xorMask;
            v8bf af[FI], bfr[FJ];
#pragma unroll
            for (int f = 0; f < FI; ++f)
                af[f] = *(const v8bf*)((const char*)As + (wm * WM + f * 16 + l15) * 128 + kb);
#pragma unroll
            for (int f = 0; f < FJ; ++f)
                bfr[f] = *(const v8bf*)((const char*)Bs + (wn * WN + f * 16 + l15) * 128 + kb);
#pragma unroll
            for (int i = 0; i < FI; ++i)
#pragma unroll
                for (int j = 0; j < FJ; ++j)
                    acc[i][j] = __builtin_amdgcn_mfma_f32_16x16x32_bf16(af[i], bfr[j], acc[i][j], 0, 0, 0);
        }
        __syncthreads();
    }

    const int cc = lane & 15, r4 = (lane >> 4) << 2;
    if constexpr (MODE == 3) {
#pragma unroll
        for (int i = 0; i < FI; ++i)
#pragma unroll
            for (int r = 0; r < 4; ++r) {
                const int gm = m0 + wm * WM + i * 16 + r4 + r;
                const int s = sbjI[gm], o = objI[gm];
                const float* Ps = addMat + (size_t)s * ldAdd;
                const float* Qo = outF + (size_t)o * ldAdd;
                float p = 0.f;
#pragma unroll
                for (int j = 0; j < FJ; ++j) {
                    const int gn = n0 + wn * WN + j * 16 + cc;
                    float rv = (float)rbDot[(size_t)gm * N + gn];
                    p += rv * (acc[i][j][r] + Ps[gn] + Qo[gn] + addRow[gn]);
                }
                p += __shfl_xor(p, 1, 64);
                p += __shfl_xor(p, 2, 64);
                p += __shfl_xor(p, 4, 64);
                p += __shfl_xor(p, 8, 64);
                if (cc == 0) atomicAdd(qOut + gm, p);
            }
    } else if constexpr (MODE == 5) {
        const int mb = m0 >> 10, nb = n0 >> 10;
        const size_t DDe = (size_t)ldOut * ldOut;
#pragma unroll
        for (int i = 0; i < FI; ++i)
#pragma unroll
            for (int j = 0; j < FJ; ++j)
#pragma unroll
                for (int r = 0; r < 4; ++r) {
                    const int gm = m0 + wm * WM + i * 16 + r4 + r;
                    const int gn = n0 + wn * WN + j * 16 + cc;
                    const int gml = gm & 1023, gnl = gn & 1023;
                    float v = acc[i][j][r];
                    if (mb == 2) {
                        outB2[(size_t)gml * 2048 + gn] = (__bf16)v;
                    } else {
                        int blk;
                        if (mb == 0) { blk = nb ? 0 : 1; if (nb) v += addMat[(size_t)gml * ldAdd + gnl]; }
                        else         { blk = nb ? 2 : 3; if (!nb) v += addRow[(size_t)gml * ldAdd + gnl]; }
                        outB[blk * DDe + (size_t)gnl * ldOut + gml] = (__bf16)v;
                    }
                }
    } else {
#pragma unroll
        for (int i = 0; i < FI; ++i)
#pragma unroll
            for (int j = 0; j < FJ; ++j)
#pragma unroll
                for (int r = 0; r < 4; ++r) {
                    const int gm = m0 + wm * WM + i * 16 + r4 + r;
                    const int gn = n0 + wn * WN + j * 16 + cc;
                    float v = acc[i][j][r];
                    if constexpr (MODE == 0) {
                        if (addMat) v += addMat[(size_t)gm * ldAdd + gn];
                        outB[(size_t)gm * ldOut + gn] = (__bf16)v;
                    } else if constexpr (MODE == 2) {
                        outF[(size_t)gm * ldOut + gn] = v;
                    } else {  // MODE 4
                        float u = addMat[(size_t)gm * ldAdd + gn];
                        if (maskRow[gm]) u += v + addRow[gn];
                        outF[(size_t)gm * ldOut + gn] = u;
                    }
                }
    }
}

// ---------------- small custom kernels ----------------

__global__ __launch_bounds__(256) void beta_kernel(
    const float* __restrict__ b_rel, const float* __restrict__ b_sbj, const float* __restrict__ b_obj,
    const float* __restrict__ Wsr, const float* __restrict__ Wor,
    float* __restrict__ bs, float* __restrict__ bo, int D, int rowsPerChunk) {
    const int col = blockIdx.x * 256 + threadIdx.x;
    if (col >= D) return;
    const int r0 = blockIdx.y * rowsPerChunk;
    const float* W = (blockIdx.z == 0) ? Wsr : Wor;
    float acc = 0.f;
    if (blockIdx.y == 0) acc = (blockIdx.z == 0) ? b_sbj[col] : b_obj[col];
    const int rEnd = min(r0 + rowsPerChunk, D);
    for (int r = r0; r < rEnd; ++r)
        acc += b_rel[r] * W[(size_t)r * D + col];
    float* out = (blockIdx.z == 0) ? bs : bo;
    atomicAdd(out + col, acc);
}

// pb[d] = sum_j bs[j]*Ko[d][j] + bo[j]*Ks[d][j];  KoKs = [D][2048] = [Ko | Ks]
__global__ __launch_bounds__(256) void pbeta_kernel(const float* __restrict__ bs,
                                                    const float* __restrict__ bo,
                                                    const __bf16* __restrict__ KoKs,
                                                    float* __restrict__ pb, int D) {
    int d = blockIdx.x * 4 + (threadIdx.x >> 6);
    int lane = threadIdx.x & 63;
    float a = 0.f;
    for (int j = lane; j < D; j += 64)
        a += bs[j] * (float)KoKs[(size_t)d * 2048 + j] + bo[j] * (float)KoKs[(size_t)d * 2048 + 1024 + j];
    a = wave_reduce_sum(a);
    if (lane == 0) pb[d] = a;
}

// ACBD = [A | C | B | D] row blocks of width D, ld = 4D
__global__ __launch_bounds__(256) void node_kernel(
    const __bf16* __restrict__ ACBD,
    const float* __restrict__ bs, const float* __restrict__ bo,
    float* __restrict__ nodeS, float* __restrict__ nodeO, int D) {
    int n = blockIdx.x * 4 + (threadIdx.x >> 6);
    int lane = threadIdx.x & 63;
    int d0 = lane * 16;
    const __bf16* row = ACBD + (size_t)n * 4 * D;
    const __bf16* pa = row + d0;
    const __bf16* pc = row + D + d0;
    const __bf16* pB = row + 2 * D + d0;
    const __bf16* pd = row + 3 * D + d0;
    float s1 = 0.f, s2 = 0.f;
#pragma unroll
    for (int u = 0; u < 16; ++u) {
        float a = (float)pa[u], c = (float)pc[u], b = (float)pB[u], dd = (float)pd[u];
        float vs_ = bs[d0 + u], vo_ = bo[d0 + u];
        s1 += a * c + a * vo_ + vs_ * c;
        s2 += b * dd + b * vo_ + vs_ * dd;
    }
    s1 = wave_reduce_sum(s1);
    s2 = wave_reduce_sum(s2);
    if (lane == 0) { nodeS[n] = s1; nodeO[n] = s2; }
}

// logits[e] = (q[e] + nodeS[s] + nodeO[o] + G_AD[s][o] + G_BC[o][s]) * scale
__global__ __launch_bounds__(256) void edge_scalar_kernel(
    const float* __restrict__ q,
    const float* __restrict__ nodeS, const float* __restrict__ nodeO,
    const float* __restrict__ G_AD, const float* __restrict__ G_BC,
    const int* __restrict__ sbj, const int* __restrict__ obj,
    float* __restrict__ logits, int E, int Nn, float scale) {
    int e = blockIdx.x * 256 + threadIdx.x;
    if (e >= E) return;
    int s = sbj[e], o = obj[e];
    logits[e] = (q[e] + nodeS[s] + nodeO[o] +
                 G_AD[(size_t)s * Nn + o] + G_BC[(size_t)o * Nn + s]) * scale;
}

__global__ __launch_bounds__(256) void segmax_kernel(const float* __restrict__ logits,
                                                     const int* __restrict__ sbj,
                                                     const int* __restrict__ obj,
                                                     unsigned* __restrict__ mS,
                                                     unsigned* __restrict__ mO, int E) {
    int e = blockIdx.x * 256 + threadIdx.x;
    if (e >= E) return;
    unsigned k = fenc(logits[e]);
    atomicMax(mS + sbj[e], k);
    atomicMax(mO + obj[e], k);
}

__global__ __launch_bounds__(256) void expsum_kernel(const float* __restrict__ logits,
                                                     const int* __restrict__ sbj,
                                                     const int* __restrict__ obj,
                                                     const unsigned* __restrict__ mS,
                                                     const unsigned* __restrict__ mO,
                                                     float* __restrict__ es, float* __restrict__ eo,
                                                     float* __restrict__ sumS, float* __restrict__ sumO,
                                                     int E) {
    int e = blockIdx.x * 256 + threadIdx.x;
    if (e >= E) return;
    float l = logits[e];
    int s = sbj[e], o = obj[e];
    float a = expf(l - fdec(mS[s]));
    es[e] = a;
    atomicAdd(sumS + s, a);
    float b = expf(l - fdec(mO[o]));
    eo[e] = b;
    atomicAdd(sumO + o, b);
}

__global__ __launch_bounds__(256) void scatter_kernel(const float* __restrict__ es,
                                                      const float* __restrict__ eo,
                                                      const float* __restrict__ sumS,
                                                      const float* __restrict__ sumO,
                                                      const int* __restrict__ sbj,
                                                      const int* __restrict__ obj,
                                                      float* __restrict__ S, int* __restrict__ inv,
                                                      int E, int Nn) {
    int e = blockIdx.x * 256 + threadIdx.x;
    if (e >= E) return;
    int s = sbj[e], o = obj[e];
    atomicAdd(S + (size_t)s * Nn + o, es[e] / sumS[s]);
    atomicAdd(S + (size_t)o * Nn + s, eo[e] / sumO[o]);
    inv[s] = 1;
    inv[o] = 1;
}

// ---------------- host launcher ----------------

extern "C" void kernel_launch(void* const* d_in, const int* in_sizes, int n_in,
                              void* d_out, int out_size, void* d_ws, size_t ws_size,
                              hipStream_t stream) {
    const float* V     = (const float*)d_in[0];
    const float* relv  = (const float*)d_in[1];
    const float* W_rel = (const float*)d_in[2];
    const float* b_rel = (const float*)d_in[3];
    const float* W_sbj = (const float*)d_in[4];
    const float* b_sbj = (const float*)d_in[5];
    const float* W_obj = (const float*)d_in[6];
    const float* b_obj = (const float*)d_in[7];
    const float* W_ctx = (const float*)d_in[8];
    const float* b_ctx = (const float*)d_in[9];
    const int* sbj = (const int*)d_in[10];
    const int* obj = (const int*)d_in[11];

    const int D  = in_sizes[3];
    const int E  = in_sizes[10];
    const int Nn = in_sizes[12];
    const size_t DD = (size_t)D * D;

    const float* Ws_v = W_sbj;
    const float* Ws_r = W_sbj + DD;
    const float* Wo_v = W_obj;
    const float* Wo_r = W_obj + DD;

    char* ws = (char*)d_ws;
    size_t off = 0;
    auto alloc = [&](size_t bytes) -> void* {
        void* p = (void*)(ws + off);
        off += (bytes + 255) & ~(size_t)255;
        return p;
    };

    // persistent
    __bf16* relv_b = (__bf16*)alloc((size_t)E * D * 2);
    __bf16* Vb     = (__bf16*)alloc((size_t)Nn * D * 2);
    __bf16* VbT    = (__bf16*)alloc((size_t)D * Nn * 2);
    __bf16* ZT_b   = (__bf16*)alloc(DD * 2);
    __bf16* KoKs   = (__bf16*)alloc((size_t)D * 2 * D * 2);   // [D][2048] = [Ko | Ks]
    __bf16* ACBD   = (__bf16*)alloc((size_t)Nn * 4 * D * 2);  // [Nn][4D] = [A|C|B|D]
    // region R1: Wr_all (3DD bf16) ... later G_AD+G_BC (2*Nn*Nn f32)
    size_t r1 = off;
    __bf16* Wr_all = (__bf16*)(ws + r1);
    float*  G_AD   = (float*)(ws + r1);
    float*  G_BC   = G_AD + (size_t)Nn * Nn;
    {
        size_t a = 3 * DD * 2, b = 2 * (size_t)Nn * Nn * 4;
        off += ((a > b ? a : b) + 255) & ~(size_t)255;
    }
    // region R2: WoWs_T (2DD bf16: [Wo_rT ; Ws_rT]) ... later W_ctxT
    size_t r2 = off;
    __bf16* WoWs_T = (__bf16*)(ws + r2);
    __bf16* W_ctxT = (__bf16*)(ws + r2);
    off += 2 * DD * 2;
    // region R3: MT_all (4DD bf16: [Ms^T;Mc^T;Mb^T;Md^T]) ... later Pm+Qm
    size_t r3 = off;
    __bf16* MT_all = (__bf16*)(ws + r3);
    float*  Pm     = (float*)(ws + r3);
    float*  Qm     = Pm + (size_t)Nn * D;
    {
        size_t a = 4 * DD * 2, b = 2 * (size_t)Nn * D * 4;
        off += ((a > b ? a : b) + 255) & ~(size_t)255;
    }
    float* pb     = (float*)alloc((size_t)D * 4);
    float* nodeS  = (float*)alloc((size_t)Nn * 4);
    float* nodeO  = (float*)alloc((size_t)Nn * 4);
    float* logits = (float*)alloc((size_t)E * 4);
    float* es     = (float*)alloc((size_t)E * 4);
    float* eo     = (float*)alloc((size_t)E * 4);
    size_t zbeg = off;
    float* S      = (float*)alloc((size_t)Nn * Nn * 4);
    float* q      = (float*)alloc((size_t)E * 4);
    float* bs     = (float*)alloc((size_t)D * 4);
    float* bo     = (float*)alloc((size_t)D * 4);
    unsigned* mS  = (unsigned*)alloc((size_t)Nn * 4);
    unsigned* mO  = (unsigned*)alloc((size_t)Nn * 4);
    float* sumS   = (float*)alloc((size_t)Nn * 4);
    float* sumO   = (float*)alloc((size_t)Nn * 4);
    int* inv      = (int*)alloc((size_t)Nn * 4);
    size_t zend = off;
    __bf16* Sb    = (__bf16*)alloc((size_t)Nn * Nn * 2);
    __bf16* ctx_b = (__bf16*)alloc((size_t)Nn * D * 2);
    (void)ws_size; (void)n_in; (void)out_size;

    float* outVj = (float*)d_out + (size_t)E * D;

    // 1. zero atomic buffers
    hipMemsetAsync(ws + zbeg, 0, zend - zbeg, stream);

    // 2. conversions (passthrough fused with relv cvt)
    auto cvt = [&](const float* in, __bf16* out, size_t n) {
        int blocks = (int)((n / 4 + 255) / 256);
        cvt_f32_bf16<<<dim3(blocks), dim3(256), 0, stream>>>(in, out, (long long)n);
    };
    auto cvtT = [&](const float* in, __bf16* out, int R, int C) {
        cvt_t_bf16<<<dim3(C / 32, R / 32), dim3(256), 0, stream>>>(in, out, R, C);
    };
    {
        long long n = (long long)E * D;
        copy_cvt<<<dim3((int)(n / 4 / 256)), dim3(256), 0, stream>>>(relv, (float*)d_out, relv_b, n);
    }
    cvt(W_rel, Wr_all, 3 * DD);
    cvt(V, Vb, (size_t)Nn * D);
    cvtT(Wo_r, WoWs_T, D, D);          // rows 0..D-1  = Wo_rT
    cvtT(Ws_r, WoWs_T + DD, D, D);     // rows D..2D-1 = Ws_rT
    cvtT(V, VbT, Nn, D);

    // 3. bias projections
    beta_kernel<<<dim3((D + 255) / 256, 32, 2), dim3(256), 0, stream>>>(
        b_rel, b_sbj, b_obj, Ws_r, Wo_r, bs, bo, D, (D + 31) / 32);

    // 4. GEMM launcher
    auto G = [&](auto modeTag, auto bigTag, const __bf16* A, int ldA, const __bf16* Bt, int ldB,
                 int M, int N2, int K, int nz, long zA, long zB, long zOut,
                 const float* addMat, int ldAdd, float* outF, __bf16* outB, int ldOut,
                 __bf16* outB2, const __bf16* rbD, float* qO, const float* addRow, const int* mask,
                 const int* sbjI = nullptr, const int* objI = nullptr) {
        constexpr int BT = decltype(bigTag)::value ? 128 : 64;
        gemm_gl<decltype(modeTag)::value, decltype(bigTag)::value>
            <<<dim3(M / BT, N2 / BT, nz), dim3(256), 0, stream>>>(
                A, ldA, Bt, ldB, M, N2, K, zA, zB, zOut, addMat, ldAdd, outF, outB, ldOut,
                outB2, rbD, qO, addRow, mask, sbjI, objI);
    };
    using M0 = std::integral_constant<int, 0>;
    using M2 = std::integral_constant<int, 2>;
    using M3 = std::integral_constant<int, 3>;
    using M4 = std::integral_constant<int, 4>;
    using M5 = std::integral_constant<int, 5>;
    using SMALL = std::integral_constant<bool, false>;
    using LARGE = std::integral_constant<bool, true>;

    // 5. merged W-side precompute: [Wr_s;Wr_o;Wr_r] @ [Wo_r | Ws_r]  (3072 x 2048 x 1024)
    //    -> MT_all blocks (transposed, +Ws_v/+Wo_v) and KoKs = [Ko|Ks]
    G(M5{}, LARGE{}, Wr_all, D, WoWs_T, D, 3 * D, 2 * D, D, 1, 0, 0, 0,
      Ws_v, D, nullptr, MT_all, D, KoKs, nullptr, nullptr, Wo_v, nullptr);
    // W_ctxT now safe to overwrite R2
    cvtT(W_ctx, W_ctxT, D, D);
    // ZT = Ko @ Ks^T
    G(M0{}, SMALL{}, KoKs + 0, 2 * D, KoKs + D, 2 * D, D, D, D, 1, 0, 0, 0,
      nullptr, 0, nullptr, ZT_b, D, nullptr, nullptr, nullptr, nullptr, nullptr);
    pbeta_kernel<<<dim3(D / 4), dim3(256), 0, stream>>>(bs, bo, KoKs, pb, D);

    // 6. fused N-side projections: ACBD = Vb @ MT_all^T  (768 x 4096)
    G(M0{}, SMALL{}, Vb, D, MT_all, D, Nn, 4 * D, D, 1, 0, 0, 0,
      nullptr, 0, nullptr, ACBD, 4 * D, nullptr, nullptr, nullptr, nullptr, nullptr);

    // 7. batched Grams (z=0: A@D^T -> G_AD, z=1: B@C^T -> G_BC), overwrite R1
    G(M2{}, SMALL{}, ACBD + 0 * D, 4 * D, ACBD + 3 * D, 4 * D, Nn, Nn, D, 2,
      2 * (long)D, -2 * (long)D, (long)Nn * Nn,
      nullptr, 0, G_AD, nullptr, Nn, nullptr, nullptr, nullptr, nullptr, nullptr);
    // batched P/Q (K=2048): z=0: [A|C]@[Ko|Ks]^T -> Pm, z=1: [B|D]@... -> Qm (overwrite R3)
    G(M2{}, SMALL{}, ACBD + 0 * D, 4 * D, KoKs, 2 * D, Nn, D, 2 * D, 2,
      2 * (long)D, 0, (long)Nn * D,
      nullptr, 0, Pm, nullptr, D, nullptr, nullptr, nullptr, nullptr, nullptr);

    node_kernel<<<dim3(Nn / 4), dim3(256), 0, stream>>>(ACBD, bs, bo, nodeS, nodeO, D);

    // 8. heavy: q[e] = (relv @ Z) . relv + relv . (Pm[s] + Qm[o] + pb)   (fused epilogue)
    G(M3{}, LARGE{}, relv_b, D, ZT_b, D, E, D, D, 1, 0, 0, 0,
      Pm, D, Qm, nullptr, 0, nullptr, relv_b, q, pb, nullptr, sbj, obj);

    // 9. scalar logits + segment softmaxes + scatter
    edge_scalar_kernel<<<dim3(E / 256), dim3(256), 0, stream>>>(
        q, nodeS, nodeO, G_AD, G_BC, sbj, obj, logits, E, Nn, 1.0f / sqrtf((float)D));
    segmax_kernel<<<dim3(E / 256), dim3(256), 0, stream>>>(logits, sbj, obj, mS, mO, E);
    expsum_kernel<<<dim3(E / 256), dim3(256), 0, stream>>>(logits, sbj, obj, mS, mO, es, eo, sumS, sumO, E);
    scatter_kernel<<<dim3(E / 256), dim3(256), 0, stream>>>(es, eo, sumS, sumO, sbj, obj, S, inv, E, Nn);

    // 10. ctx = S @ V ; vj update
    cvt(S, Sb, (size_t)Nn * Nn);
    G(M0{}, SMALL{}, Sb, Nn, VbT, Nn, Nn, D, Nn, 1, 0, 0, 0,
      nullptr, 0, nullptr, ctx_b, D, nullptr, nullptr, nullptr, nullptr, nullptr);
    G(M4{}, SMALL{}, ctx_b, D, W_ctxT, D, Nn, D, D, 1, 0, 0, 0,
      V, D, outVj, nullptr, D, nullptr, nullptr, nullptr, b_ctx, inv);
}

// Round 6
// 374.026 us; speedup vs baseline: 2.6444x; 1.0170x over previous
//
#include <hip/hip_runtime.h>
#include <hip/hip_bf16.h>
#include <math.h>
#include <type_traits>

typedef __bf16 v8bf __attribute__((ext_vector_type(8)));
typedef __bf16 v4bf __attribute__((ext_vector_type(4)));
typedef float  v4f  __attribute__((ext_vector_type(4)));

__device__ __forceinline__ float wave_reduce_sum(float v) {
#pragma unroll
    for (int m = 1; m < 64; m <<= 1) v += __shfl_xor(v, m, 64);
    return v;
}

__device__ __forceinline__ unsigned fenc(float x) {
    unsigned u = __float_as_uint(x);
    return (u & 0x80000000u) ? ~u : (u | 0x80000000u);
}
__device__ __forceinline__ float fdec(unsigned k) {
    return (k & 0x80000000u) ? __uint_as_float(k ^ 0x80000000u) : __uint_as_float(~k);
}

__device__ __forceinline__ void gload16(const void* g, void* l) {
    __builtin_amdgcn_global_load_lds((const __attribute__((address_space(1))) void*)g,
                                     (__attribute__((address_space(3))) void*)l, 16, 0, 0);
}

// ---------------- conversion kernels ----------------

__global__ __launch_bounds__(256) void cvt_f32_bf16(const float* __restrict__ in,
                                                    __bf16* __restrict__ out, long long n) {
    long long i = ((long long)blockIdx.x * 256 + threadIdx.x) * 4;
    if (i >= n) return;
    v4f v = *(const v4f*)(in + i);
    v4bf o;
    o[0] = (__bf16)v[0]; o[1] = (__bf16)v[1]; o[2] = (__bf16)v[2]; o[3] = (__bf16)v[3];
    *(v4bf*)(out + i) = o;
}

// fused: outCopy = in (f32), outB = bf16(in). Reads the 100 MB relv once.
__global__ __launch_bounds__(256) void copy_cvt(const float* __restrict__ in,
                                                float* __restrict__ outCopy,
                                                __bf16* __restrict__ outB, long long n) {
    long long i = ((long long)blockIdx.x * 256 + threadIdx.x) * 4;
    if (i >= n) return;
    v4f v = *(const v4f*)(in + i);
    *(v4f*)(outCopy + i) = v;
    v4bf o;
    o[0] = (__bf16)v[0]; o[1] = (__bf16)v[1]; o[2] = (__bf16)v[2]; o[3] = (__bf16)v[3];
    *(v4bf*)(outB + i) = o;
}

// out[c][r] = (bf16) in[r][c];  R,C multiples of 32
__global__ __launch_bounds__(256) void cvt_t_bf16(const float* __restrict__ in,
                                                  __bf16* __restrict__ out, int R, int C) {
    __shared__ float tile[32][33];
    int cb = blockIdx.x * 32, rb = blockIdx.y * 32;
    int tx = threadIdx.x & 31, ty = threadIdx.x >> 5;
#pragma unroll
    for (int i = 0; i < 32; i += 8)
        tile[ty + i][tx] = in[(size_t)(rb + ty + i) * C + cb + tx];
    __syncthreads();
#pragma unroll
    for (int i = 0; i < 32; i += 8)
        out[(size_t)(cb + ty + i) * R + rb + tx] = (__bf16)tile[tx][ty + i];
}

// batched 4x DxD transpose-convert (z picks the pair)
__global__ __launch_bounds__(256) void cvt_t4_bf16(
    const float* __restrict__ in0, __bf16* __restrict__ out0,
    const float* __restrict__ in1, __bf16* __restrict__ out1,
    const float* __restrict__ in2, __bf16* __restrict__ out2,
    const float* __restrict__ in3, __bf16* __restrict__ out3, int Dd) {
    __shared__ float tile[32][33];
    const float* in = (blockIdx.z == 0) ? in0 : (blockIdx.z == 1) ? in1 : (blockIdx.z == 2) ? in2 : in3;
    __bf16* out = (blockIdx.z == 0) ? out0 : (blockIdx.z == 1) ? out1 : (blockIdx.z == 2) ? out2 : out3;
    int cb = blockIdx.x * 32, rb = blockIdx.y * 32;
    int tx = threadIdx.x & 31, ty = threadIdx.x >> 5;
#pragma unroll
    for (int i = 0; i < 32; i += 8)
        tile[ty + i][tx] = in[(size_t)(rb + ty + i) * Dd + cb + tx];
    __syncthreads();
#pragma unroll
    for (int i = 0; i < 32; i += 8)
        out[(size_t)(cb + ty + i) * Dd + rb + tx] = (__bf16)tile[tx][ty + i];
}

// ---- bf16 MFMA GEMM, m97 structure + XOR-swizzled LDS (rule #21) ----
// out = A (MxK, ldA) @ Bt^T (Bt is NxK, ldB).  grid.z batching via zA/zB/zOut.
// MODE 0: outB (bf16, plain, ldOut) = acc (+addMat f32 [ldAdd] if non-null)
// MODE 2: outF (f32, plain, ldOut)  = acc
// MODE 3: fused logits partial: atomicAdd(qOut[m],
//           sum_n rbDot[m][n]*(acc[m][n] + addMat[s[m]][n] + outF[o[m]][n] + addRow[n]))
// MODE 4: outF[m][n] = addMat[m][n] + (maskRow[m] ? acc + addRow[n] : 0)
// MODE 6: MT-combo (M=2D, N=2D): A=[Wo_rT;Ws_rT], Bt=[Wr_s;Wr_o].
//         quadrant (mb,nb) -> MT_all block {(1,0)->0 Ms^T(+rbDot=Ws_vT),
//         (0,0)->1 Mc^T, (1,1)->2 Mb^T, (0,1)->3 Md^T(+outB2=Wo_vT)};
//         plain coalesced writes into outB[blk*D*D + gml*D + gnl].
template <int MODE, bool BIG>
__global__ __launch_bounds__(256, 4) void gemm_gl(
    const __bf16* __restrict__ Ap, int ldA,
    const __bf16* __restrict__ Btp, int ldB,
    int M, int N, int K,
    long zA, long zB, long zOut,
    const float* __restrict__ addMat, int ldAdd,
    float* __restrict__ outF,
    __bf16* __restrict__ outB, int ldOut,
    __bf16* __restrict__ outB2,
    const __bf16* __restrict__ rbDot,
    float* __restrict__ qOut,
    const float* __restrict__ addRow,
    const int* __restrict__ maskRow,
    const int* __restrict__ sbjI,
    const int* __restrict__ objI) {
    constexpr int BM = BIG ? 128 : 64;
    constexpr int BN = BIG ? 128 : 64;
    constexpr int WM = BM / 2, WN = BN / 2;
    constexpr int FI = WM / 16, FJ = WN / 16;
    constexpr int NLA = (BM * 64) / 2048;
    constexpr int NLB = (BN * 64) / 2048;

    __shared__ alignas(16) __bf16 As[BM * 64];
    __shared__ alignas(16) __bf16 Bs[BN * 64];

    Ap  += zA * (long)blockIdx.z;
    Btp += zB * (long)blockIdx.z;
    outF += zOut * (long)blockIdx.z;

    const int m0 = blockIdx.x * BM, n0 = blockIdx.y * BN;
    const int t = threadIdx.x, lane = t & 63, wid = t >> 6;
    const int wm = wid >> 1, wn = wid & 1;
    const int rA = t >> 3;
    const int cSw = (t & 7) ^ (rA & 7);            // swizzled 16B-chunk (involution)

    v4f acc[FI][FJ] = {};

    const int l15 = lane & 15;
    const int xorMask = (l15 & 7) << 4;            // read-side XOR (bytes)

    for (int kt = 0; kt < K; kt += 64) {
#pragma unroll
        for (int i = 0; i < NLA; ++i)
            gload16(Ap + (size_t)(m0 + i * 32 + rA) * ldA + kt + cSw * 8,
                    (char*)As + i * 4096 + wid * 1024);
#pragma unroll
        for (int i = 0; i < NLB; ++i)
            gload16(Btp + (size_t)(n0 + i * 32 + rA) * ldB + kt + cSw * 8,
                    (char*)Bs + i * 4096 + wid * 1024);
        __syncthreads();
#pragma unroll
        for (int ks = 0; ks < 2; ++ks) {
            const int kb = (ks * 64 + ((lane >> 4) << 4)) ^ xorMask;
            v8bf af[FI], bfr[FJ];
#pragma unroll
            for (int f = 0; f < FI; ++f)
                af[f] = *(const v8bf*)((const char*)As + (wm * WM + f * 16 + l15) * 128 + kb);
#pragma unroll
            for (int f = 0; f < FJ; ++f)
                bfr[f] = *(const v8bf*)((const char*)Bs + (wn * WN + f * 16 + l15) * 128 + kb);
#pragma unroll
            for (int i = 0; i < FI; ++i)
#pragma unroll
                for (int j = 0; j < FJ; ++j)
                    acc[i][j] = __builtin_amdgcn_mfma_f32_16x16x32_bf16(af[i], bfr[j], acc[i][j], 0, 0, 0);
        }
        __syncthreads();
    }

    const int cc = lane & 15, r4 = (lane >> 4) << 2;
    if constexpr (MODE == 3) {
#pragma unroll
        for (int i = 0; i < FI; ++i)
#pragma unroll
            for (int r = 0; r < 4; ++r) {
                const int gm = m0 + wm * WM + i * 16 + r4 + r;
                const int s = sbjI[gm], o = objI[gm];
                const float* Ps = addMat + (size_t)s * ldAdd;
                const float* Qo = outF + (size_t)o * ldAdd;
                float p = 0.f;
#pragma unroll
                for (int j = 0; j < FJ; ++j) {
                    const int gn = n0 + wn * WN + j * 16 + cc;
                    float rv = (float)rbDot[(size_t)gm * N + gn];
                    p += rv * (acc[i][j][r] + Ps[gn] + Qo[gn] + addRow[gn]);
                }
                p += __shfl_xor(p, 1, 64);
                p += __shfl_xor(p, 2, 64);
                p += __shfl_xor(p, 4, 64);
                p += __shfl_xor(p, 8, 64);
                if (cc == 0) atomicAdd(qOut + gm, p);
            }
    } else if constexpr (MODE == 6) {
        const int mb = m0 >> 10, nb = n0 >> 10;
        const int blk = (mb == 0) ? (nb ? 3 : 1) : (nb ? 2 : 0);
        const __bf16* addB = (blk == 0) ? rbDot : (blk == 3 ? outB2 : nullptr);
        const size_t DDe = (size_t)ldOut * ldOut;
        __bf16* dst = outB + (size_t)blk * DDe;
#pragma unroll
        for (int i = 0; i < FI; ++i)
#pragma unroll
            for (int j = 0; j < FJ; ++j)
#pragma unroll
                for (int r = 0; r < 4; ++r) {
                    const int gml = (m0 + wm * WM + i * 16 + r4 + r) & 1023;
                    const int gnl = (n0 + wn * WN + j * 16 + cc) & 1023;
                    float v = acc[i][j][r];
                    if (addB) v += (float)addB[(size_t)gml * ldOut + gnl];
                    dst[(size_t)gml * ldOut + gnl] = (__bf16)v;
                }
    } else {
#pragma unroll
        for (int i = 0; i < FI; ++i)
#pragma unroll
            for (int j = 0; j < FJ; ++j)
#pragma unroll
                for (int r = 0; r < 4; ++r) {
                    const int gm = m0 + wm * WM + i * 16 + r4 + r;
                    const int gn = n0 + wn * WN + j * 16 + cc;
                    float v = acc[i][j][r];
                    if constexpr (MODE == 0) {
                        if (addMat) v += addMat[(size_t)gm * ldAdd + gn];
                        outB[(size_t)gm * ldOut + gn] = (__bf16)v;
                    } else if constexpr (MODE == 2) {
                        outF[(size_t)gm * ldOut + gn] = v;
                    } else {  // MODE 4
                        float u = addMat[(size_t)gm * ldAdd + gn];
                        if (maskRow[gm]) u += v + addRow[gn];
                        outF[(size_t)gm * ldOut + gn] = u;
                    }
                }
    }
}

// ---------------- small custom kernels ----------------

__global__ __launch_bounds__(256) void beta_kernel(
    const float* __restrict__ b_rel, const float* __restrict__ b_sbj, const float* __restrict__ b_obj,
    const float* __restrict__ Wsr, const float* __restrict__ Wor,
    float* __restrict__ bs, float* __restrict__ bo, int D, int rowsPerChunk) {
    const int col = blockIdx.x * 256 + threadIdx.x;
    if (col >= D) return;
    const int r0 = blockIdx.y * rowsPerChunk;
    const float* W = (blockIdx.z == 0) ? Wsr : Wor;
    float acc = 0.f;
    if (blockIdx.y == 0) acc = (blockIdx.z == 0) ? b_sbj[col] : b_obj[col];
    const int rEnd = min(r0 + rowsPerChunk, D);
    for (int r = r0; r < rEnd; ++r)
        acc += b_rel[r] * W[(size_t)r * D + col];
    float* out = (blockIdx.z == 0) ? bs : bo;
    atomicAdd(out + col, acc);
}

// pb[d] = sum_j bs[j]*Ko[d][j] + bo[j]*Ks[d][j];  KoKs = [D][2048] = [Ko | Ks]
__global__ __launch_bounds__(256) void pbeta_kernel(const float* __restrict__ bs,
                                                    const float* __restrict__ bo,
                                                    const __bf16* __restrict__ KoKs,
                                                    float* __restrict__ pb, int D) {
    int d = blockIdx.x * 4 + (threadIdx.x >> 6);
    int lane = threadIdx.x & 63;
    float a = 0.f;
    for (int j = lane; j < D; j += 64)
        a += bs[j] * (float)KoKs[(size_t)d * 2048 + j] + bo[j] * (float)KoKs[(size_t)d * 2048 + 1024 + j];
    a = wave_reduce_sum(a);
    if (lane == 0) pb[d] = a;
}

// ACBD = [A | C | B | D] row blocks of width D, ld = 4D
__global__ __launch_bounds__(256) void node_kernel(
    const __bf16* __restrict__ ACBD,
    const float* __restrict__ bs, const float* __restrict__ bo,
    float* __restrict__ nodeS, float* __restrict__ nodeO, int D) {
    int n = blockIdx.x * 4 + (threadIdx.x >> 6);
    int lane = threadIdx.x & 63;
    int d0 = lane * 16;
    const __bf16* row = ACBD + (size_t)n * 4 * D;
    const __bf16* pa = row + d0;
    const __bf16* pc = row + D + d0;
    const __bf16* pB = row + 2 * D + d0;
    const __bf16* pd = row + 3 * D + d0;
    float s1 = 0.f, s2 = 0.f;
#pragma unroll
    for (int u = 0; u < 16; ++u) {
        float a = (float)pa[u], c = (float)pc[u], b = (float)pB[u], dd = (float)pd[u];
        float vs_ = bs[d0 + u], vo_ = bo[d0 + u];
        s1 += a * c + a * vo_ + vs_ * c;
        s2 += b * dd + b * vo_ + vs_ * dd;
    }
    s1 = wave_reduce_sum(s1);
    s2 = wave_reduce_sum(s2);
    if (lane == 0) { nodeS[n] = s1; nodeO[n] = s2; }
}

// logits[e] = (q[e]+nodeS[s]+nodeO[o]+G_AD[s][o]+G_BC[o][s])*scale; fused segment max
__global__ __launch_bounds__(256) void edge_lmax_kernel(
    const float* __restrict__ q,
    const float* __restrict__ nodeS, const float* __restrict__ nodeO,
    const float* __restrict__ G_AD, const float* __restrict__ G_BC,
    const int* __restrict__ sbj, const int* __restrict__ obj,
    float* __restrict__ logits, unsigned* __restrict__ mS, unsigned* __restrict__ mO,
    int E, int Nn, float scale) {
    int e = blockIdx.x * 256 + threadIdx.x;
    if (e >= E) return;
    int s = sbj[e], o = obj[e];
    float l = (q[e] + nodeS[s] + nodeO[o] +
               G_AD[(size_t)s * Nn + o] + G_BC[(size_t)o * Nn + s]) * scale;
    logits[e] = l;
    unsigned k = fenc(l);
    atomicMax(mS + s, k);
    atomicMax(mO + o, k);
}

__global__ __launch_bounds__(256) void expsum_kernel(const float* __restrict__ logits,
                                                     const int* __restrict__ sbj,
                                                     const int* __restrict__ obj,
                                                     const unsigned* __restrict__ mS,
                                                     const unsigned* __restrict__ mO,
                                                     float* __restrict__ es, float* __restrict__ eo,
                                                     float* __restrict__ sumS, float* __restrict__ sumO,
                                                     int E) {
    int e = blockIdx.x * 256 + threadIdx.x;
    if (e >= E) return;
    float l = logits[e];
    int s = sbj[e], o = obj[e];
    float a = expf(l - fdec(mS[s]));
    es[e] = a;
    atomicAdd(sumS + s, a);
    float b = expf(l - fdec(mO[o]));
    eo[e] = b;
    atomicAdd(sumO + o, b);
}

__global__ __launch_bounds__(256) void scatter_kernel(const float* __restrict__ es,
                                                      const float* __restrict__ eo,
                                                      const float* __restrict__ sumS,
                                                      const float* __restrict__ sumO,
                                                      const int* __restrict__ sbj,
                                                      const int* __restrict__ obj,
                                                      float* __restrict__ S, int* __restrict__ inv,
                                                      int E, int Nn) {
    int e = blockIdx.x * 256 + threadIdx.x;
    if (e >= E) return;
    int s = sbj[e], o = obj[e];
    atomicAdd(S + (size_t)s * Nn + o, es[e] / sumS[s]);
    atomicAdd(S + (size_t)o * Nn + s, eo[e] / sumO[o]);
    inv[s] = 1;
    inv[o] = 1;
}

// ---------------- host launcher ----------------

extern "C" void kernel_launch(void* const* d_in, const int* in_sizes, int n_in,
                              void* d_out, int out_size, void* d_ws, size_t ws_size,
                              hipStream_t stream) {
    const float* V     = (const float*)d_in[0];
    const float* relv  = (const float*)d_in[1];
    const float* W_rel = (const float*)d_in[2];
    const float* b_rel = (const float*)d_in[3];
    const float* W_sbj = (const float*)d_in[4];
    const float* b_sbj = (const float*)d_in[5];
    const float* W_obj = (const float*)d_in[6];
    const float* b_obj = (const float*)d_in[7];
    const float* W_ctx = (const float*)d_in[8];
    const float* b_ctx = (const float*)d_in[9];
    const int* sbj = (const int*)d_in[10];
    const int* obj = (const int*)d_in[11];

    const int D  = in_sizes[3];
    const int E  = in_sizes[10];
    const int Nn = in_sizes[12];
    const size_t DD = (size_t)D * D;

    const float* Ws_v = W_sbj;
    const float* Ws_r = W_sbj + DD;
    const float* Wo_v = W_obj;
    const float* Wo_r = W_obj + DD;

    char* ws = (char*)d_ws;
    size_t off = 0;
    auto alloc = [&](size_t bytes) -> void* {
        void* p = (void*)(ws + off);
        off += (bytes + 255) & ~(size_t)255;
        return p;
    };

    // persistent
    __bf16* relv_b = (__bf16*)alloc((size_t)E * D * 2);
    __bf16* Vb     = (__bf16*)alloc((size_t)Nn * D * 2);
    __bf16* VbT    = (__bf16*)alloc((size_t)D * Nn * 2);
    __bf16* ZT_b   = (__bf16*)alloc(DD * 2);
    __bf16* KoKs   = (__bf16*)alloc((size_t)D * 2 * D * 2);   // [D][2048] = [Ko | Ks]
    __bf16* ACBD   = (__bf16*)alloc((size_t)Nn * 4 * D * 2);  // [Nn][4D] = [A|C|B|D]
    __bf16* Ws_vT  = (__bf16*)alloc(DD * 2);
    __bf16* Wo_vT  = (__bf16*)alloc(DD * 2);
    // region R1: Wr_all (3DD bf16) ... later G_AD+G_BC (2*Nn*Nn f32)
    size_t r1 = off;
    __bf16* Wr_all = (__bf16*)(ws + r1);
    float*  G_AD   = (float*)(ws + r1);
    float*  G_BC   = G_AD + (size_t)Nn * Nn;
    {
        size_t a = 3 * DD * 2, b = 2 * (size_t)Nn * Nn * 4;
        off += ((a > b ? a : b) + 255) & ~(size_t)255;
    }
    // region R2: WoWs_T (2DD bf16: [Wo_rT ; Ws_rT]) ... later W_ctxT
    size_t r2 = off;
    __bf16* WoWs_T = (__bf16*)(ws + r2);
    __bf16* W_ctxT = (__bf16*)(ws + r2);
    off += 2 * DD * 2;
    // region R3: MT_all (4DD bf16: [Ms^T;Mc^T;Mb^T;Md^T]) ... later Pm+Qm
    size_t r3 = off;
    __bf16* MT_all = (__bf16*)(ws + r3);
    float*  Pm     = (float*)(ws + r3);
    float*  Qm     = Pm + (size_t)Nn * D;
    {
        size_t a = 4 * DD * 2, b = 2 * (size_t)Nn * D * 4;
        off += ((a > b ? a : b) + 255) & ~(size_t)255;
    }
    float* pb     = (float*)alloc((size_t)D * 4);
    float* nodeS  = (float*)alloc((size_t)Nn * 4);
    float* nodeO  = (float*)alloc((size_t)Nn * 4);
    float* logits = (float*)alloc((size_t)E * 4);
    float* es     = (float*)alloc((size_t)E * 4);
    float* eo     = (float*)alloc((size_t)E * 4);
    size_t zbeg = off;
    float* S      = (float*)alloc((size_t)Nn * Nn * 4);
    float* q      = (float*)alloc((size_t)E * 4);
    float* bs     = (float*)alloc((size_t)D * 4);
    float* bo     = (float*)alloc((size_t)D * 4);
    unsigned* mS  = (unsigned*)alloc((size_t)Nn * 4);
    unsigned* mO  = (unsigned*)alloc((size_t)Nn * 4);
    float* sumS   = (float*)alloc((size_t)Nn * 4);
    float* sumO   = (float*)alloc((size_t)Nn * 4);
    int* inv      = (int*)alloc((size_t)Nn * 4);
    size_t zend = off;
    __bf16* Sb    = (__bf16*)alloc((size_t)Nn * Nn * 2);
    __bf16* ctx_b = (__bf16*)alloc((size_t)Nn * D * 2);
    (void)ws_size; (void)n_in; (void)out_size;

    float* outVj = (float*)d_out + (size_t)E * D;

    // 1. zero atomic buffers
    hipMemsetAsync(ws + zbeg, 0, zend - zbeg, stream);

    // 2. conversions (passthrough fused with relv cvt)
    auto cvt = [&](const float* in, __bf16* out, size_t n) {
        int blocks = (int)((n / 4 + 255) / 256);
        cvt_f32_bf16<<<dim3(blocks), dim3(256), 0, stream>>>(in, out, (long long)n);
    };
    auto cvtT = [&](const float* in, __bf16* out, int R, int C) {
        cvt_t_bf16<<<dim3(C / 32, R / 32), dim3(256), 0, stream>>>(in, out, R, C);
    };
    {
        long long n = (long long)E * D;
        copy_cvt<<<dim3((int)(n / 4 / 256)), dim3(256), 0, stream>>>(relv, (float*)d_out, relv_b, n);
    }
    cvt(W_rel, Wr_all, 3 * DD);
    cvt(V, Vb, (size_t)Nn * D);
    // batched DxD transposes: Wo_r, Ws_r, Ws_v, Wo_v
    cvt_t4_bf16<<<dim3(D / 32, D / 32, 4), dim3(256), 0, stream>>>(
        Wo_r, WoWs_T, Ws_r, WoWs_T + DD, Ws_v, Ws_vT, Wo_v, Wo_vT, D);
    cvtT(V, VbT, Nn, D);

    // 3. bias projections
    beta_kernel<<<dim3((D + 255) / 256, 32, 2), dim3(256), 0, stream>>>(
        b_rel, b_sbj, b_obj, Ws_r, Wo_r, bs, bo, D, (D + 31) / 32);

    // 4. GEMM launcher
    auto G = [&](auto modeTag, auto bigTag, const __bf16* A, int ldA, const __bf16* Bt, int ldB,
                 int M, int N2, int K, int nz, long zA, long zB, long zOut,
                 const float* addMat, int ldAdd, float* outF, __bf16* outB, int ldOut,
                 __bf16* outB2, const __bf16* rbD, float* qO, const float* addRow, const int* mask,
                 const int* sbjI = nullptr, const int* objI = nullptr) {
        constexpr int BT = decltype(bigTag)::value ? 128 : 64;
        gemm_gl<decltype(modeTag)::value, decltype(bigTag)::value>
            <<<dim3(M / BT, N2 / BT, nz), dim3(256), 0, stream>>>(
                A, ldA, Bt, ldB, M, N2, K, zA, zB, zOut, addMat, ldAdd, outF, outB, ldOut,
                outB2, rbD, qO, addRow, mask, sbjI, objI);
    };
    using M0 = std::integral_constant<int, 0>;
    using M2 = std::integral_constant<int, 2>;
    using M3 = std::integral_constant<int, 3>;
    using M4 = std::integral_constant<int, 4>;
    using M6 = std::integral_constant<int, 6>;
    using SMALL = std::integral_constant<bool, false>;
    using LARGE = std::integral_constant<bool, true>;

    // 5a. MT-combo: [Wo_rT;Ws_rT] @ [Wr_s;Wr_o]^T (2048x2048x1024) -> MT_all, plain writes
    G(M6{}, LARGE{}, WoWs_T, D, Wr_all, D, 2 * D, 2 * D, D, 1, 0, 0, 0,
      nullptr, 0, nullptr, MT_all, D, Wo_vT, Ws_vT, nullptr, nullptr, nullptr);
    // 5b. KoKs = Wr_r @ [Wo_rT;Ws_rT]^T -> [Ko|Ks] plain (1024x2048x1024)
    G(M0{}, LARGE{}, Wr_all + 2 * DD, D, WoWs_T, D, D, 2 * D, D, 1, 0, 0, 0,
      nullptr, 0, nullptr, KoKs, 2 * D, nullptr, nullptr, nullptr, nullptr, nullptr);
    // W_ctxT now safe to overwrite R2
    cvtT(W_ctx, W_ctxT, D, D);
    // ZT = Ko @ Ks^T
    G(M0{}, SMALL{}, KoKs + 0, 2 * D, KoKs + D, 2 * D, D, D, D, 1, 0, 0, 0,
      nullptr, 0, nullptr, ZT_b, D, nullptr, nullptr, nullptr, nullptr, nullptr);
    pbeta_kernel<<<dim3(D / 4), dim3(256), 0, stream>>>(bs, bo, KoKs, pb, D);

    // 6. fused N-side projections: ACBD = Vb @ MT_all^T  (768 x 4096)
    G(M0{}, SMALL{}, Vb, D, MT_all, D, Nn, 4 * D, D, 1, 0, 0, 0,
      nullptr, 0, nullptr, ACBD, 4 * D, nullptr, nullptr, nullptr, nullptr, nullptr);

    // 7. batched Grams (z=0: A@D^T -> G_AD, z=1: B@C^T -> G_BC), overwrite R1
    G(M2{}, SMALL{}, ACBD + 0 * D, 4 * D, ACBD + 3 * D, 4 * D, Nn, Nn, D, 2,
      2 * (long)D, -2 * (long)D, (long)Nn * Nn,
      nullptr, 0, G_AD, nullptr, Nn, nullptr, nullptr, nullptr, nullptr, nullptr);
    // batched P/Q (K=2048): z=0: [A|C]@[Ko|Ks]^T -> Pm, z=1: [B|D]@... -> Qm (overwrite R3)
    G(M2{}, SMALL{}, ACBD + 0 * D, 4 * D, KoKs, 2 * D, Nn, D, 2 * D, 2,
      2 * (long)D, 0, (long)Nn * D,
      nullptr, 0, Pm, nullptr, D, nullptr, nullptr, nullptr, nullptr, nullptr);

    node_kernel<<<dim3(Nn / 4), dim3(256), 0, stream>>>(ACBD, bs, bo, nodeS, nodeO, D);

    // 8. heavy: q[e] = (relv @ Z) . relv + relv . (Pm[s] + Qm[o] + pb)   (fused epilogue)
    G(M3{}, LARGE{}, relv_b, D, ZT_b, D, E, D, D, 1, 0, 0, 0,
      Pm, D, Qm, nullptr, 0, nullptr, relv_b, q, pb, nullptr, sbj, obj);

    // 9. fused scalar logits + segment max, then expsum + scatter
    edge_lmax_kernel<<<dim3(E / 256), dim3(256), 0, stream>>>(
        q, nodeS, nodeO, G_AD, G_BC, sbj, obj, logits, mS, mO, E, Nn, 1.0f / sqrtf((float)D));
    expsum_kernel<<<dim3(E / 256), dim3(256), 0, stream>>>(logits, sbj, obj, mS, mO, es, eo, sumS, sumO, E);
    scatter_kernel<<<dim3(E / 256), dim3(256), 0, stream>>>(es, eo, sumS, sumO, sbj, obj, S, inv, E, Nn);

    // 10. ctx = S @ V ; vj update
    cvt(S, Sb, (size_t)Nn * Nn);
    G(M0{}, SMALL{}, Sb, Nn, VbT, Nn, Nn, D, Nn, 1, 0, 0, 0,
      nullptr, 0, nullptr, ctx_b, D, nullptr, nullptr, nullptr, nullptr, nullptr);
    G(M4{}, SMALL{}, ctx_b, D, W_ctxT, D, Nn, D, D, 1, 0, 0, 0,
      V, D, outVj, nullptr, D, nullptr, nullptr, nullptr, b_ctx, inv);
}